// Round 13
// baseline (1730.611 us; speedup 1.0000x reference)
//
#include <hip/hip_runtime.h>
#include <hip/hip_bf16.h>
#include <hip/hip_fp16.h>
#include <math.h>

// ---------------------------------------------------------------------------
// PointsToImage: ball-query (K=32, R=0.1) -> PointNetConv msg=[x_j, pos_j-pos_dst]
// -> Linear(66,128) -> masked-BatchNorm -> ReLU -> Linear(128,64) -> scatter-max
// into pixel nodes, output [B=32, F=64, 32, 32] fp32.
//
// R13: launch fusion 6 -> 4.
//  - k_finalize folded into k_y (last-block ticket: block 255 re-reduces the
//    256x516 partials + 1024 DEF tails and writes scsh).
//  - k_gather folded into k_out (per-pixel completion counter: the last query
//    of a pixel performs the max-gather over its contiguous scratch slots +
//    selfbuf and stores out). 32k device atomics total.
//  - ticket + pixdone zero-initialized by k_bq's 32 prep blocks.
// Pipeline (4 launches): k_bq -> k_y(+finalize) -> k_self -> k_out(+gather)
// ---------------------------------------------------------------------------

#define NPTS   32768
#define KNB    32
#define BN_EPS 1e-5f

// workspace layout (bytes) -- same envelope as R12 (max 39,344,128)
#define WS_NBRS     0u           // int[NPTS*KNB]      = 4194304
#define WS_NBRCNT   4194304u     // int[NPTS]          = 131072
#define WS_PIXDONE  4325376u     // int[NPTS]          = 131072
#define WS_KYCNT    4456448u     // int[1]
#define WS_SCSH     4719616u     // float[256]
#define WS_W2B      4720640u     // ushort[8192]       (W2 B-frag, fp16)
#define WS_PART     4737024u     // float[256*516]     = 528384
#define WS_Y        5265408u     // uint[NPTS*64]      = 8388608 (yb; dead after k_self)
#define WS_SCRATCH  5265408u     // float[NPTS*64]     (OVERLAYS yb)
#define WS_WB       13654016u    // uint[NPTS*64]      = 8388608 (w, fp16 pairs)
#define WS_QCNT     22042624u    // int[NPTS]
#define WS_QSTART   22173696u    // int[NPTS]
#define WS_QLIST    22304768u    // int[NPTS]
#define WS_ISLOT    22435840u    // int[NPTS]
#define WS_SELF     22566912u    // float[NPTS*64]     = 8388608
#define WS_SHP      30955520u    // uint[NPTS*64]      = 8388608 (shp, fp16 pairs)
#define WS_BQPART   22566912u    // float[1024*3076]   = 12599296 (OVERLAYS self+shp;
                                 //   dead after k_y finalize, before k_self writes)

typedef __attribute__((ext_vector_type(8))) _Float16 half8;
typedef __attribute__((ext_vector_type(2))) _Float16 half2v;
typedef __attribute__((ext_vector_type(4))) float floatx4;

__device__ __forceinline__ unsigned short f2h_bits(float f) {
    _Float16 h = (_Float16)f;
    return *reinterpret_cast<unsigned short*>(&h);
}
__device__ __forceinline__ float bf_lo(unsigned int w) { return __uint_as_float(w << 16); }
__device__ __forceinline__ float bf_hi(unsigned int w) { return __uint_as_float(w & 0xffff0000u); }
__device__ __forceinline__ unsigned int pack_bf2(float lo, float hi) {
    __hip_bfloat162 hh = __float22bfloat162_rn(make_float2(lo, hi));
    return *reinterpret_cast<unsigned int*>(&hh);
}
__device__ __forceinline__ unsigned int pack_h2(float lo, float hi) {
    half2v hh = { (_Float16)lo, (_Float16)hi };
    return *reinterpret_cast<unsigned int*>(&hh);
}

// ------------- fused prep + ball query (1056 blocks) ------------------------
// blocks 0-31:   pixmap inversion + W2 pack + pixdone/ticket zero-init
// blocks 32-1055: ballot-prefix ball query (32 samples x 32 chunks x 32 queries)
union ShBQ {
    struct {
        float2 poss[1024];
        float accd[1024], accx[1024], accy[1024];
        unsigned long long cand[4][256];
    } bq;                                             // 28672 B
    struct {
        int cntS[1024], preS[1024], offS[1024], pixOf[1024];
        int wtot[4];
    } pm;                                             // 16400 B
};

__launch_bounds__(256)
__global__ void k_bq(const float* __restrict__ pos,
                     int* __restrict__ nbrs, int* __restrict__ nbr_cnt,
                     float* __restrict__ bqpart,
                     const float* __restrict__ W2, unsigned short* __restrict__ w2b,
                     int* __restrict__ qcnt, int* __restrict__ qstart,
                     int* __restrict__ qlist, int* __restrict__ islot,
                     int* __restrict__ pixdone, int* __restrict__ kycnt) {
    __shared__ ShBQ sh;
    int tid = threadIdx.x;

    if (blockIdx.x < 32) {
        // ---------------- prep path ----------------
        int s = blockIdx.x;
        int gt = s * 256 + tid;            // 8192 total
        {   // W2 pack: B-frag lane L holds B[k=(L>>4)*8+j][n=L&15]
            int j  = gt & 7;
            int L  = (gt >> 3) & 63;
            int ks = (gt >> 9) & 3;
            int t4 = gt >> 11;
            int k = ks * 32 + (L >> 4) * 8 + j;
            int n = t4 * 16 + (L & 15);
            w2b[gt] = f2h_bits(W2[k * 64 + n]);
        }
        if (gt == 0) *kycnt = 0;
        int base = s << 10;
        for (int i = tid; i < 1024; i += 256) pixdone[base + i] = 0;
        for (int i = tid; i < 1024; i += 256) sh.pm.cntS[i] = 0;
        __syncthreads();
        for (int ql = tid; ql < 1024; ql += 256) {
            float2 p = *(const float2*)&pos[2 * (base + ql)];
            int row = min(max((int)(p.y * 32.0f), 0), 31);
            int col = min(max((int)(p.x * 32.0f), 0), 31);
            int pixl = row * 32 + col;
            sh.pm.pixOf[ql] = pixl;
            atomicAdd(&sh.pm.cntS[pixl], 1);
        }
        __syncthreads();
        int a0 = sh.pm.cntS[4 * tid], a1 = sh.pm.cntS[4 * tid + 1];
        int a2 = sh.pm.cntS[4 * tid + 2], a3 = sh.pm.cntS[4 * tid + 3];
        int tsum = a0 + a1 + a2 + a3;
        int lane = tid & 63, wv = tid >> 6;
        int v = tsum;
        for (int o = 1; o < 64; o <<= 1) { int u = __shfl_up(v, o); if (lane >= o) v += u; }
        if (lane == 63) sh.pm.wtot[wv] = v;
        __syncthreads();
        int wbase = 0;
        for (int w = 0; w < wv; ++w) wbase += sh.pm.wtot[w];
        int excl = wbase + v - tsum;
        sh.pm.preS[4 * tid] = excl;
        sh.pm.preS[4 * tid + 1] = excl + a0;
        sh.pm.preS[4 * tid + 2] = excl + a0 + a1;
        sh.pm.preS[4 * tid + 3] = excl + a0 + a1 + a2;
        __syncthreads();
        for (int i = tid; i < 1024; i += 256) sh.pm.offS[i] = sh.pm.preS[i];
        __syncthreads();
        for (int ql = tid; ql < 1024; ql += 256) {
            int p = sh.pm.pixOf[ql];
            int slot = atomicAdd(&sh.pm.offS[p], 1);
            qlist[base + slot] = base + ql;
            islot[base + ql] = base + slot;
        }
        for (int i = tid; i < 1024; i += 256) {
            qcnt[base + i] = sh.pm.cntS[i];
            qstart[base + i] = base + sh.pm.preS[i];
        }
        return;
    }

    // ---------------- ball query path ----------------
    int bqid = blockIdx.x - 32;        // 0..1023
    int wave = tid >> 6, lane = tid & 63;
    int s = bqid >> 5;                 // sample
    int chunk = bqid & 31;             // 32 chunks of 32 queries
    int base = s << 10;
    for (int i = tid; i < 1024; i += 256) sh.bq.poss[i] = *(const float2*)&pos[2 * (base + i)];
    for (int i = tid; i < 1024; i += 256) { sh.bq.accd[i] = 0.0f; sh.bq.accx[i] = 0.0f; sh.bq.accy[i] = 0.0f; }
    __syncthreads();
    float2 pr[16];
#pragma unroll
    for (int k = 0; k < 16; ++k) pr[k] = sh.bq.poss[k * 64 + lane];
    unsigned long long lb = (1ull << lane) - 1ull;   // bits below this lane

    float aD = 0, aE = 0, aF = 0;
    for (int qi = 0; qi < 8; ++qi) {
        int ql = chunk * 32 + wave * 8 + qi;
        int q = base + ql;
        float2 qp = sh.bq.poss[ql];
        int row = min(max((int)(qp.y * 32.0f), 0), 31);
        int col = min(max((int)(qp.x * 32.0f), 0), 31);
        int pixl = row * 32 + col;
        float2 tp = sh.bq.poss[pixl];
        int cnt = 0;
        __builtin_amdgcn_wave_barrier();
#pragma unroll
        for (int k = 0; k < 16; ++k) {
            float dx = pr[k].x - qp.x, dy = pr[k].y - qp.y;
            float d2 = __fadd_rn(__fmul_rn(dx, dx), __fmul_rn(dy, dy)); // no FMA contraction
            bool pred = (d2 <= 0.01f);
            unsigned long long mask = __ballot(pred);
            if (pred) {
                int slot = cnt + (int)__popcll(mask & lb);
                if (slot < 256)
                    sh.bq.cand[wave][slot] = ((unsigned long long)__float_as_uint(d2) << 32)
                                             | (unsigned int)(k * 64 + lane);
            }
            cnt += (int)__popcll(mask);
        }
        cnt = min(cnt, 256);
        __builtin_amdgcn_wave_barrier();
        int osel = 0;
        for (int cb = 0; cb < cnt; cb += 64) {
            int i = cb + lane;
            bool sel = false;
            int j = 0;
            if (i < cnt) {
                unsigned long long key = sh.bq.cand[wave][i];
                j = (int)(key & 0xffffffffu);
                if (cnt <= KNB) {
                    sel = (j != pixl);                 // all in-radius are top-K
                } else {
                    int rank = 0;
                    for (int t = 0; t < cnt; ++t) rank += (sh.bq.cand[wave][t] < key) ? 1 : 0;
                    sel = (rank < KNB) && (j != pixl); // top-K, then remove_self_loops
                }
            }
            unsigned long long mask = __ballot(sel);
            if (sel) {
                int slot = osel + (int)__popcll(mask & lb);
                nbrs[q * KNB + slot] = base + j;
                float rx = sh.bq.poss[j].x - tp.x, ry = sh.bq.poss[j].y - tp.y;
                aD += rx * rx; aE += rx * ry; aF += ry * ry;
                atomicAdd(&sh.bq.accd[j], 1.0f);
                atomicAdd(&sh.bq.accx[j], tp.x);
                atomicAdd(&sh.bq.accy[j], tp.y);
            }
            osel += (int)__popcll(mask);
        }
        if (lane == 0) nbr_cnt[q] = osel;
    }
#pragma unroll
    for (int o = 1; o < 64; o <<= 1) {
        aD += __shfl_xor(aD, o); aE += __shfl_xor(aE, o); aF += __shfl_xor(aF, o);
    }
    __syncthreads();
    float* pb = &bqpart[bqid * 3076];
    for (int i = tid; i < 1024; i += 256) {
        pb[i] = sh.bq.accd[i]; pb[1024 + i] = sh.bq.accx[i]; pb[2048 + i] = sh.bq.accy[i];
    }
    if (tid == 0) { pb[3072] = aD; pb[3073] = aE; pb[3074] = aF; }   // DEF tails, plain store
}

// ---------------- node GEMM1 + fused nodeagg + BN stats + finalize ----------
// 256 blocks x 512 threads; block = 128 nodes; lane owns f0=2l, f1=2l+1.
// Last block (ticket) re-reduces partials + DEF tails and writes scsh.
__launch_bounds__(512)
__global__ void k_y(const float* __restrict__ x, const float* __restrict__ W1,
                    const float* __restrict__ b1, const float* __restrict__ pos,
                    const float* __restrict__ bqpart,
                    unsigned int* __restrict__ yb, float* __restrict__ partials,
                    const float* __restrict__ gamma, const float* __restrict__ beta,
                    float* __restrict__ scsh, int* __restrict__ kycnt) {
    __shared__ float w1s[64 * 128];
    __shared__ float stage[8][512];
    __shared__ float lsum[515];
    __shared__ float degS[128], stxS[128], styS[128];
    __shared__ float sDEF[3];
    __shared__ int amLast;
    int tid = threadIdx.x;
    int nblock = blockIdx.x * 128;
    for (int i = tid; i < 64 * 128; i += 512) w1s[i] = W1[i];
    for (int i = tid; i < 515; i += 512) lsum[i] = 0.0f;
    if (tid < 128) {                       // fused nodeagg: 32 chunk partials
        int n = nblock + tid;
        int s = n >> 10, off = n & 1023;
        const float* pb = &bqpart[(s * 32) * 3076];
        float d = 0, xx = 0, yy = 0;
        for (int j = 0; j < 32; ++j) {
            d  += pb[j * 3076 + off];
            xx += pb[j * 3076 + 1024 + off];
            yy += pb[j * 3076 + 2048 + off];
        }
        degS[tid] = d; stxS[tid] = xx; styS[tid] = yy;
    }
    __syncthreads();
    int wave = tid >> 6, lane = tid & 63;
    int f0 = 2 * lane, f1 = 2 * lane + 1;
    float b10 = b1[f0], b11 = b1[f1];
    float* st = &stage[wave][0];
    float P0 = 0, Q0 = 0, R0 = 0, S0 = 0, P1 = 0, Q1 = 0, R1 = 0, S1 = 0;
    float sB = 0, sC = 0, sDeg = 0;

    for (int it = 0; it < 2; ++it) {
        int nbase = nblock + (wave * 2 + it) * 8;
        __builtin_amdgcn_wave_barrier();
#pragma unroll
        for (int mm = 0; mm < 8; ++mm)
            st[mm * 64 + lane] = x[(nbase + mm) * 64 + lane];
        __builtin_amdgcn_wave_barrier();
        float z0[8], z1[8];
#pragma unroll
        for (int mm = 0; mm < 8; ++mm) { z0[mm] = b10; z1[mm] = b11; }
        for (int k4 = 0; k4 < 16; ++k4) {
            float2 wv0 = *(const float2*)&w1s[(k4 * 4 + 0) * 128 + f0];
            float2 wv1 = *(const float2*)&w1s[(k4 * 4 + 1) * 128 + f0];
            float2 wv2 = *(const float2*)&w1s[(k4 * 4 + 2) * 128 + f0];
            float2 wv3 = *(const float2*)&w1s[(k4 * 4 + 3) * 128 + f0];
#pragma unroll
            for (int mm = 0; mm < 8; ++mm) {
                float4 mk = *(const float4*)&st[mm * 64 + k4 * 4];
                z0[mm] += mk.x * wv0.x + mk.y * wv1.x + mk.z * wv2.x + mk.w * wv3.x;
                z1[mm] += mk.x * wv0.y + mk.y * wv1.y + mk.z * wv2.y + mk.w * wv3.y;
            }
        }
#pragma unroll
        for (int mm = 0; mm < 8; ++mm) {
            int n = nbase + mm;
            int li = n - nblock;
            float dg = degS[li];
            float wgt = 1.0f + dg;
            float Bn = dg * pos[2 * n]     - stxS[li];
            float Cn = dg * pos[2 * n + 1] - styS[li];
            float a = z0[mm], bq = z1[mm];
            P0 += wgt * a;  Q0 += wgt * a * a;  R0 += a * Bn;  S0 += a * Cn;
            P1 += wgt * bq; Q1 += wgt * bq * bq; R1 += bq * Bn; S1 += bq * Cn;
            sB += Bn; sC += Cn; sDeg += dg;
            yb[n * 64 + lane] = pack_bf2(a, bq);
        }
        __builtin_amdgcn_wave_barrier();
    }
    atomicAdd(&lsum[f0], P0);        atomicAdd(&lsum[f1], P1);
    atomicAdd(&lsum[128 + f0], Q0);  atomicAdd(&lsum[128 + f1], Q1);
    atomicAdd(&lsum[256 + f0], R0);  atomicAdd(&lsum[256 + f1], R1);
    atomicAdd(&lsum[384 + f0], S0);  atomicAdd(&lsum[384 + f1], S1);
    if (lane == 0) {
        atomicAdd(&lsum[512], sB);
        atomicAdd(&lsum[513], sC);
        atomicAdd(&lsum[514], sDeg);
    }
    __syncthreads();
    for (int i = tid; i < 515; i += 512) partials[blockIdx.x * 516 + i] = lsum[i];
    // ---- last-block finalize ----
    __threadfence();
    if (tid == 0) amLast = (atomicAdd(kycnt, 1) == 255) ? 1 : 0;
    __syncthreads();
    if (!amLast) return;
    __threadfence();
    if (tid < 3) sDEF[tid] = 0.0f;
    __syncthreads();
    for (int i = tid; i < 515; i += 512) {
        float s = 0;
        for (int b = 0; b < 256; ++b) s += partials[b * 516 + i];
        lsum[i] = s;
    }
    {   // sum the 1024 per-block DEF tails
        float td = 0, te = 0, tf = 0;
        for (int b = tid; b < 1024; b += 512) {
            const float* pb = &bqpart[b * 3076 + 3072];
            td += pb[0]; te += pb[1]; tf += pb[2];
        }
        atomicAdd(&sDEF[0], td); atomicAdd(&sDEF[1], te); atomicAdd(&sDEF[2], tf);
    }
    __syncthreads();
    if (tid < 128) {
        int f = tid;
        float P = lsum[f], Q = lsum[128 + f], R = lsum[256 + f], S = lsum[384 + f];
        float SB = lsum[512], SC = lsum[513], SDeg = lsum[514];
        float u = W1[8192 + f], v = W1[8320 + f];
        float cntv = 32768.0f + SDeg;
        float mean = (P + u * SB + v * SC) / cntv;
        float E2 = (Q + 2.0f * u * R + 2.0f * v * S
                    + u * u * sDEF[0] + 2.0f * u * v * sDEF[1] + v * v * sDEF[2]) / cntv;
        float var = E2 - mean * mean;
        float sc = gamma[f] / sqrtf(var + BN_EPS);
        scsh[f] = sc;
        scsh[128 + f] = beta[f] - mean * sc;
    }
}

// ---------- self pass (MFMA f16) + w/shp precompute (fp16) ------------------
__launch_bounds__(256)
__global__ void k_self(const unsigned int* __restrict__ yb, const float* __restrict__ pos,
                       const float* __restrict__ W1, const float* __restrict__ scsh,
                       const unsigned short* __restrict__ w2b, const float* __restrict__ b2,
                       const int* __restrict__ qcnt,
                       unsigned int* __restrict__ wbuf, unsigned int* __restrict__ shpbuf,
                       float* __restrict__ selfbuf, float* __restrict__ out) {
    __shared__ unsigned short hbuf[4][16 * 136];   // 272 B row stride
    int tid = threadIdx.x, wave = tid >> 6, lane = tid & 63;
    unsigned short* hb = hbuf[wave];
    half8 bfrag[4][4];
#pragma unroll
    for (int t = 0; t < 4; ++t)
#pragma unroll
        for (int ks = 0; ks < 4; ++ks)
            bfrag[t][ks] = *(const half8*)&w2b[((t * 4 + ks) * 64 + lane) * 8];
    int f0 = 2 * lane;
    float sc0 = scsh[f0],     sh0 = scsh[128 + f0];
    float sc1 = scsh[f0 + 1], sh1 = scsh[129 + f0];
    float u0 = W1[8192 + f0], v0 = W1[8320 + f0];
    float u1 = W1[8193 + f0], v1 = W1[8321 + f0];
    float b2v0 = b2[(lane & 15)],      b2v1 = b2[16 + (lane & 15)];
    float b2v2 = b2[32 + (lane & 15)], b2v3 = b2[48 + (lane & 15)];

    int nbase = (blockIdx.x * 4 + wave) * 16;
#pragma unroll
    for (int c = 0; c < 2; ++c) {
        unsigned int yw[8];
#pragma unroll
        for (int j = 0; j < 8; ++j)
            yw[j] = yb[(nbase + c * 8 + j) * 64 + lane];
#pragma unroll
        for (int j = 0; j < 8; ++j) {
            int e = c * 8 + j;
            int nn = nbase + e;
            float y0 = bf_lo(yw[j]), y1 = bf_hi(yw[j]);
            float h0 = fmaxf(y0 * sc0 + sh0, 0.0f);
            float h1 = fmaxf(y1 * sc1 + sh1, 0.0f);
            *(unsigned int*)&hb[e * 136 + f0] = pack_h2(h0, h1);
            float px = pos[2 * nn], py = pos[2 * nn + 1];
            float ts0 = (px * u0 + py * v0) * sc0;
            float ts1 = (px * u1 + py * v1) * sc1;
            wbuf[nn * 64 + lane]   = pack_h2(y0 * sc0 + ts0, y1 * sc1 + ts1);
            shpbuf[nn * 64 + lane] = pack_h2(sh0 - ts0, sh1 - ts1);
        }
    }
    __builtin_amdgcn_wave_barrier();
    floatx4 acc0 = {0,0,0,0}, acc1 = {0,0,0,0}, acc2 = {0,0,0,0}, acc3 = {0,0,0,0};
#pragma unroll
    for (int ks = 0; ks < 4; ++ks) {
        half8 a = *(const half8*)&hb[(lane & 15) * 136 + ks * 32 + (lane >> 4) * 8];
        acc0 = __builtin_amdgcn_mfma_f32_16x16x32_f16(a, bfrag[0][ks], acc0, 0, 0, 0);
        acc1 = __builtin_amdgcn_mfma_f32_16x16x32_f16(a, bfrag[1][ks], acc1, 0, 0, 0);
        acc2 = __builtin_amdgcn_mfma_f32_16x16x32_f16(a, bfrag[2][ks], acc2, 0, 0, 0);
        acc3 = __builtin_amdgcn_mfma_f32_16x16x32_f16(a, bfrag[3][ks], acc3, 0, 0, 0);
    }
    int nrow = nbase + (lane >> 4) * 4;
#pragma unroll
    for (int r = 0; r < 4; ++r) {
        int n = nrow + r;
        float o0 = acc0[r] + b2v0, o1 = acc1[r] + b2v1;
        float o2 = acc2[r] + b2v2, o3 = acc3[r] + b2v3;
        selfbuf[n * 64 + (lane & 15)]      = o0;   // contiguous copy for k_out's gather
        selfbuf[n * 64 + 16 + (lane & 15)] = o1;
        selfbuf[n * 64 + 32 + (lane & 15)] = o2;
        selfbuf[n * 64 + 48 + (lane & 15)] = o3;
        if (qcnt[n] == 0) {                 // k_out's gather overwrites qcnt>0 nodes
            int obase = (n >> 10) * 65536 + (n & 1023);
            out[obase + ((lane & 15)) * 1024]      = o0;
            out[obase + (16 + (lane & 15)) * 1024] = o1;
            out[obase + (32 + (lane & 15)) * 1024] = o2;
            out[obase + (48 + (lane & 15)) * 1024] = o3;
        }
    }
}

// ---------- neighbor pass + fused per-pixel gather --------------------------
__launch_bounds__(256)
__global__ void k_out(const unsigned int* __restrict__ wbuf,
                      const unsigned int* __restrict__ shpbuf,
                      const float* __restrict__ pos,
                      const unsigned short* __restrict__ w2b, const float* __restrict__ b2,
                      const int* __restrict__ nbrs, const int* __restrict__ nbr_cnt,
                      const int* __restrict__ islot, const int* __restrict__ qcnt,
                      const int* __restrict__ qstart, const float* __restrict__ selfbuf,
                      int* __restrict__ pixdone, float* __restrict__ scratch,
                      float* __restrict__ out) {
    int tid = threadIdx.x, wave = tid >> 6, lane = tid & 63;
    half8 bfrag[4][4];
#pragma unroll
    for (int t = 0; t < 4; ++t)
#pragma unroll
        for (int ks = 0; ks < 4; ++ks)
            bfrag[t][ks] = *(const half8*)&w2b[((t * 4 + ks) * 64 + lane) * 8];
    float b2l = b2[lane];
    int em = lane & 15;                  // edge-in-tile this lane's A-frag covers
    int koff = (lane >> 4) * 4;          // dword offset of this lane's 8 features
    int wid = blockIdx.x * 4 + wave;     // 16384 waves, 2 queries each

    for (int qi = 0; qi < 2; ++qi) {
        int q = wid * 2 + qi;
        int m = nbr_cnt[q];              // m <= 32
        int b = q >> 10;
        float om0[4], om1[4], om2[4], om3[4];
#pragma unroll
        for (int r = 0; r < 4; ++r) { om0[r] = -INFINITY; om1[r] = -INFINITY; om2[r] = -INFINITY; om3[r] = -INFINITY; }
        float qx = pos[2 * q], qy = pos[2 * q + 1];
        int row = min(max((int)(qy * 32.0f), 0), 31);
        int col = min(max((int)(qx * 32.0f), 0), 31);
        int pixq = (b << 10) + row * 32 + col;

        if (m > 0) {
            uint4 sv[4];
#pragma unroll
            for (int ks = 0; ks < 4; ++ks)
                sv[ks] = *(const uint4*)&shpbuf[pixq * 64 + ks * 16 + koff];
            int nv = (lane < m) ? nbrs[q * KNB + lane] : 0;
            int src0 = __shfl(nv, em);
            int src1 = __shfl(nv, 16 + em);
            bool two = (m > 16);
            uint4 g0[4], g1[4];
            const unsigned int* wp0 = &wbuf[src0 * 64 + koff];
#pragma unroll
            for (int ks = 0; ks < 4; ++ks) g0[ks] = *(const uint4*)&wp0[ks * 16];
            if (two) {
                const unsigned int* wp1 = &wbuf[src1 * 64 + koff];
#pragma unroll
                for (int ks = 0; ks < 4; ++ks) g1[ks] = *(const uint4*)&wp1[ks * 16];
            }
            int rowb = (lane >> 4) * 4;
            // ---- tile 0 ----
            {
                floatx4 a0 = {0,0,0,0}, a1 = {0,0,0,0}, a2 = {0,0,0,0}, a3 = {0,0,0,0};
#pragma unroll
                for (int ks = 0; ks < 4; ++ks) {
                    union { unsigned int u[4]; half8 h8; } af;
#pragma unroll
                    for (int qd = 0; qd < 4; ++qd) {
                        unsigned int wd = (qd == 0) ? g0[ks].x : (qd == 1) ? g0[ks].y : (qd == 2) ? g0[ks].z : g0[ks].w;
                        unsigned int sd = (qd == 0) ? sv[ks].x : (qd == 1) ? sv[ks].y : (qd == 2) ? sv[ks].z : sv[ks].w;
                        half2v wh = *reinterpret_cast<half2v*>(&wd);
                        half2v shh = *reinterpret_cast<half2v*>(&sd);
                        half2v zz = { (_Float16)0.0f, (_Float16)0.0f };
                        half2v hh = __builtin_elementwise_max(wh + shh, zz);
                        af.u[qd] = *reinterpret_cast<unsigned int*>(&hh);
                    }
                    a0 = __builtin_amdgcn_mfma_f32_16x16x32_f16(af.h8, bfrag[0][ks], a0, 0, 0, 0);
                    a1 = __builtin_amdgcn_mfma_f32_16x16x32_f16(af.h8, bfrag[1][ks], a1, 0, 0, 0);
                    a2 = __builtin_amdgcn_mfma_f32_16x16x32_f16(af.h8, bfrag[2][ks], a2, 0, 0, 0);
                    a3 = __builtin_amdgcn_mfma_f32_16x16x32_f16(af.h8, bfrag[3][ks], a3, 0, 0, 0);
                }
#pragma unroll
                for (int r = 0; r < 4; ++r) {
                    if (rowb + r < m) {
                        om0[r] = fmaxf(om0[r], a0[r]);
                        om1[r] = fmaxf(om1[r], a1[r]);
                        om2[r] = fmaxf(om2[r], a2[r]);
                        om3[r] = fmaxf(om3[r], a3[r]);
                    }
                }
            }
            // ---- tile 1 ----
            if (two) {
                floatx4 a0 = {0,0,0,0}, a1 = {0,0,0,0}, a2 = {0,0,0,0}, a3 = {0,0,0,0};
#pragma unroll
                for (int ks = 0; ks < 4; ++ks) {
                    union { unsigned int u[4]; half8 h8; } af;
#pragma unroll
                    for (int qd = 0; qd < 4; ++qd) {
                        unsigned int wd = (qd == 0) ? g1[ks].x : (qd == 1) ? g1[ks].y : (qd == 2) ? g1[ks].z : g1[ks].w;
                        unsigned int sd = (qd == 0) ? sv[ks].x : (qd == 1) ? sv[ks].y : (qd == 2) ? sv[ks].z : sv[ks].w;
                        half2v wh = *reinterpret_cast<half2v*>(&wd);
                        half2v shh = *reinterpret_cast<half2v*>(&sd);
                        half2v zz = { (_Float16)0.0f, (_Float16)0.0f };
                        half2v hh = __builtin_elementwise_max(wh + shh, zz);
                        af.u[qd] = *reinterpret_cast<unsigned int*>(&hh);
                    }
                    a0 = __builtin_amdgcn_mfma_f32_16x16x32_f16(af.h8, bfrag[0][ks], a0, 0, 0, 0);
                    a1 = __builtin_amdgcn_mfma_f32_16x16x32_f16(af.h8, bfrag[1][ks], a1, 0, 0, 0);
                    a2 = __builtin_amdgcn_mfma_f32_16x16x32_f16(af.h8, bfrag[2][ks], a2, 0, 0, 0);
                    a3 = __builtin_amdgcn_mfma_f32_16x16x32_f16(af.h8, bfrag[3][ks], a3, 0, 0, 0);
                }
#pragma unroll
                for (int r = 0; r < 4; ++r) {
                    int e = 16 + rowb + r;
                    if (e < m) {
                        om0[r] = fmaxf(om0[r], a0[r]);
                        om1[r] = fmaxf(om1[r], a1[r]);
                        om2[r] = fmaxf(om2[r], a2[r]);
                        om3[r] = fmaxf(om3[r], a3[r]);
                    }
                }
            }
        }
        float w0 = fmaxf(fmaxf(om0[0], om0[1]), fmaxf(om0[2], om0[3]));
        float w1 = fmaxf(fmaxf(om1[0], om1[1]), fmaxf(om1[2], om1[3]));
        float w2 = fmaxf(fmaxf(om2[0], om2[1]), fmaxf(om2[2], om2[3]));
        float w3 = fmaxf(fmaxf(om3[0], om3[1]), fmaxf(om3[2], om3[3]));
        w0 = fmaxf(w0, __shfl_xor(w0, 16)); w0 = fmaxf(w0, __shfl_xor(w0, 32));
        w1 = fmaxf(w1, __shfl_xor(w1, 16)); w1 = fmaxf(w1, __shfl_xor(w1, 32));
        w2 = fmaxf(w2, __shfl_xor(w2, 16)); w2 = fmaxf(w2, __shfl_xor(w2, 32));
        w3 = fmaxf(w3, __shfl_xor(w3, 16)); w3 = fmaxf(w3, __shfl_xor(w3, 32));
        int g4 = lane >> 4;   // feature = g4*16 + (lane&15) = lane
        float vf = (g4 == 0) ? w0 : (g4 == 1) ? w1 : (g4 == 2) ? w2 : w3;
        vf += b2l;            // m==0 -> -inf: ignored by the gather's max
        scratch[islot[q] * 64 + lane] = vf;    // plain coalesced store, no atomics

        // ---- fused gather: last query of this pixel reduces + stores out ----
        __threadfence();
        int done = 0;
        if (lane == 0) done = atomicAdd(&pixdone[pixq], 1);
        done = __shfl(done, 0);
        int c = qcnt[pixq];
        if (done == c - 1) {
            __threadfence();
            int qs = qstart[pixq];
            float v = selfbuf[pixq * 64 + lane];
            for (int i = 0; i < c; ++i)
                v = fmaxf(v, scratch[(qs + i) * 64 + lane]);
            out[(pixq >> 10) * 65536 + lane * 1024 + (pixq & 1023)] = v;
        }
    }
}

extern "C" void kernel_launch(void* const* d_in, const int* in_sizes, int n_in,
                              void* d_out, int out_size, void* d_ws, size_t ws_size,
                              hipStream_t stream) {
    const float* x     = (const float*)d_in[0];
    const float* pos   = (const float*)d_in[1];
    // d_in[2] = batch (unused: points are sorted, b = idx >> 10)
    const float* W1    = (const float*)d_in[3];
    const float* b1    = (const float*)d_in[4];
    const float* gamma = (const float*)d_in[5];
    const float* beta  = (const float*)d_in[6];
    const float* W2    = (const float*)d_in[7];
    const float* b2    = (const float*)d_in[8];
    float* out = (float*)d_out;
    char* ws = (char*)d_ws;
    int*   nbrs     = (int*)(ws + WS_NBRS);
    int*   nbr_cnt  = (int*)(ws + WS_NBRCNT);
    int*   pixdone  = (int*)(ws + WS_PIXDONE);
    int*   kycnt    = (int*)(ws + WS_KYCNT);
    float* scsh     = (float*)(ws + WS_SCSH);
    unsigned short* w2b = (unsigned short*)(ws + WS_W2B);
    float* partials = (float*)(ws + WS_PART);
    unsigned int* yb = (unsigned int*)(ws + WS_Y);
    float* scratch  = (float*)(ws + WS_SCRATCH);        // overlays yb (dead after k_self)
    unsigned int* wbuf = (unsigned int*)(ws + WS_WB);
    int* qcnt   = (int*)(ws + WS_QCNT);
    int* qstart = (int*)(ws + WS_QSTART);
    int* qlist  = (int*)(ws + WS_QLIST);
    int* islot  = (int*)(ws + WS_ISLOT);
    float* selfbuf = (float*)(ws + WS_SELF);
    unsigned int* shpbuf = (unsigned int*)(ws + WS_SHP);
    float* bqpart   = (float*)(ws + WS_BQPART);         // overlays self+shp (dead before k_self)

    k_bq<<<1056, 256, 0, stream>>>(pos, nbrs, nbr_cnt, bqpart, W2, w2b,
                                   qcnt, qstart, qlist, islot, pixdone, kycnt);
    k_y<<<256, 512, 0, stream>>>(x, W1, b1, pos, bqpart, yb, partials,
                                 gamma, beta, scsh, kycnt);
    k_self<<<NPTS / 64, 256, 0, stream>>>(yb, pos, W1, scsh, w2b, b2, qcnt,
                                          wbuf, shpbuf, selfbuf, out);
    k_out<<<NPTS / 8, 256, 0, stream>>>(wbuf, shpbuf, pos, w2b, b2,
                                        nbrs, nbr_cnt, islot, qcnt, qstart,
                                        selfbuf, pixdone, scratch, out);
}

// Round 14
// 277.778 us; speedup vs baseline: 6.2302x; 6.2302x over previous
//
#include <hip/hip_runtime.h>
#include <hip/hip_bf16.h>
#include <hip/hip_fp16.h>
#include <math.h>

// ---------------------------------------------------------------------------
// PointsToImage: ball-query (K=32, R=0.1) -> PointNetConv msg=[x_j, pos_j-pos_dst]
// -> Linear(66,128) -> masked-BatchNorm -> ReLU -> Linear(128,64) -> scatter-max
// into pixel nodes, output [B=32, F=64, 32, 32] fp32.
//
// R14: R13's fused per-query __threadfence gather was catastrophic (43 ms
// dispatch: device-scope fences serialize across non-coherent XCD L2s).
// Reverted k_out/k_gather to R12 forms. Kept k_y+finalize fusion (fence once
// per block only). NEW: XCD-aware block swizzle in k_out -- all 128 blocks of
// a sample land on one XCD (s == blockIdx&7 mod 8), so the sample's wbuf/shp/
// nbrs/scratch slices (~900 KB) stay L2-resident (4 samples/XCD ~= 3.6 MB).
// Pipeline (5 launches): k_bq -> k_y(+finalize) -> k_self -> k_out -> k_gather
// ---------------------------------------------------------------------------

#define NPTS   32768
#define KNB    32
#define BN_EPS 1e-5f

// workspace layout (bytes)
#define WS_NBRS     0u           // int[NPTS*KNB]      = 4194304
#define WS_NBRCNT   4194304u     // int[NPTS]          = 131072
#define WS_KYCNT    4456448u     // int[1]
#define WS_SCSH     4719616u     // float[256]
#define WS_W2B      4720640u     // ushort[8192]       (W2 B-frag, fp16)
#define WS_PART     4737024u     // float[256*516]     = 528384
#define WS_Y        5265408u     // uint[NPTS*64]      = 8388608 (yb; dead after k_self)
#define WS_SCRATCH  5265408u     // float[NPTS*64]     (OVERLAYS yb)
#define WS_WB       13654016u    // uint[NPTS*64]      = 8388608 (w, fp16 pairs)
#define WS_QCNT     22042624u    // int[NPTS]
#define WS_QSTART   22173696u    // int[NPTS]
#define WS_QLIST    22304768u    // int[NPTS]
#define WS_ISLOT    22435840u    // int[NPTS]
#define WS_SELF     22566912u    // float[NPTS*64]     = 8388608
#define WS_SHP      30955520u    // uint[NPTS*64]      = 8388608 (shp, fp16 pairs)
#define WS_BQPART   22566912u    // float[1024*3076]   = 12599296 (OVERLAYS self+shp;
                                 //   dead after k_y finalize, before k_self writes)

typedef __attribute__((ext_vector_type(8))) _Float16 half8;
typedef __attribute__((ext_vector_type(2))) _Float16 half2v;
typedef __attribute__((ext_vector_type(4))) float floatx4;

__device__ __forceinline__ unsigned short f2h_bits(float f) {
    _Float16 h = (_Float16)f;
    return *reinterpret_cast<unsigned short*>(&h);
}
__device__ __forceinline__ float bf_lo(unsigned int w) { return __uint_as_float(w << 16); }
__device__ __forceinline__ float bf_hi(unsigned int w) { return __uint_as_float(w & 0xffff0000u); }
__device__ __forceinline__ unsigned int pack_bf2(float lo, float hi) {
    __hip_bfloat162 hh = __float22bfloat162_rn(make_float2(lo, hi));
    return *reinterpret_cast<unsigned int*>(&hh);
}
__device__ __forceinline__ unsigned int pack_h2(float lo, float hi) {
    half2v hh = { (_Float16)lo, (_Float16)hi };
    return *reinterpret_cast<unsigned int*>(&hh);
}

// ------------- fused prep + ball query (1056 blocks) ------------------------
union ShBQ {
    struct {
        float2 poss[1024];
        float accd[1024], accx[1024], accy[1024];
        unsigned long long cand[4][256];
    } bq;                                             // 28672 B
    struct {
        int cntS[1024], preS[1024], offS[1024], pixOf[1024];
        int wtot[4];
    } pm;                                             // 16400 B
};

__launch_bounds__(256)
__global__ void k_bq(const float* __restrict__ pos,
                     int* __restrict__ nbrs, int* __restrict__ nbr_cnt,
                     float* __restrict__ bqpart,
                     const float* __restrict__ W2, unsigned short* __restrict__ w2b,
                     int* __restrict__ qcnt, int* __restrict__ qstart,
                     int* __restrict__ qlist, int* __restrict__ islot,
                     int* __restrict__ kycnt) {
    __shared__ ShBQ sh;
    int tid = threadIdx.x;

    if (blockIdx.x < 32) {
        // ---------------- prep path ----------------
        int s = blockIdx.x;
        int gt = s * 256 + tid;            // 8192 total
        {   // W2 pack: B-frag lane L holds B[k=(L>>4)*8+j][n=L&15]
            int j  = gt & 7;
            int L  = (gt >> 3) & 63;
            int ks = (gt >> 9) & 3;
            int t4 = gt >> 11;
            int k = ks * 32 + (L >> 4) * 8 + j;
            int n = t4 * 16 + (L & 15);
            w2b[gt] = f2h_bits(W2[k * 64 + n]);
        }
        if (gt == 0) *kycnt = 0;
        int base = s << 10;
        for (int i = tid; i < 1024; i += 256) sh.pm.cntS[i] = 0;
        __syncthreads();
        for (int ql = tid; ql < 1024; ql += 256) {
            float2 p = *(const float2*)&pos[2 * (base + ql)];
            int row = min(max((int)(p.y * 32.0f), 0), 31);
            int col = min(max((int)(p.x * 32.0f), 0), 31);
            int pixl = row * 32 + col;
            sh.pm.pixOf[ql] = pixl;
            atomicAdd(&sh.pm.cntS[pixl], 1);
        }
        __syncthreads();
        int a0 = sh.pm.cntS[4 * tid], a1 = sh.pm.cntS[4 * tid + 1];
        int a2 = sh.pm.cntS[4 * tid + 2], a3 = sh.pm.cntS[4 * tid + 3];
        int tsum = a0 + a1 + a2 + a3;
        int lane = tid & 63, wv = tid >> 6;
        int v = tsum;
        for (int o = 1; o < 64; o <<= 1) { int u = __shfl_up(v, o); if (lane >= o) v += u; }
        if (lane == 63) sh.pm.wtot[wv] = v;
        __syncthreads();
        int wbase = 0;
        for (int w = 0; w < wv; ++w) wbase += sh.pm.wtot[w];
        int excl = wbase + v - tsum;
        sh.pm.preS[4 * tid] = excl;
        sh.pm.preS[4 * tid + 1] = excl + a0;
        sh.pm.preS[4 * tid + 2] = excl + a0 + a1;
        sh.pm.preS[4 * tid + 3] = excl + a0 + a1 + a2;
        __syncthreads();
        for (int i = tid; i < 1024; i += 256) sh.pm.offS[i] = sh.pm.preS[i];
        __syncthreads();
        for (int ql = tid; ql < 1024; ql += 256) {
            int p = sh.pm.pixOf[ql];
            int slot = atomicAdd(&sh.pm.offS[p], 1);
            qlist[base + slot] = base + ql;
            islot[base + ql] = base + slot;
        }
        for (int i = tid; i < 1024; i += 256) {
            qcnt[base + i] = sh.pm.cntS[i];
            qstart[base + i] = base + sh.pm.preS[i];
        }
        return;
    }

    // ---------------- ball query path ----------------
    int bqid = blockIdx.x - 32;        // 0..1023
    int wave = tid >> 6, lane = tid & 63;
    int s = bqid >> 5;                 // sample
    int chunk = bqid & 31;             // 32 chunks of 32 queries
    int base = s << 10;
    for (int i = tid; i < 1024; i += 256) sh.bq.poss[i] = *(const float2*)&pos[2 * (base + i)];
    for (int i = tid; i < 1024; i += 256) { sh.bq.accd[i] = 0.0f; sh.bq.accx[i] = 0.0f; sh.bq.accy[i] = 0.0f; }
    __syncthreads();
    float2 pr[16];
#pragma unroll
    for (int k = 0; k < 16; ++k) pr[k] = sh.bq.poss[k * 64 + lane];
    unsigned long long lb = (1ull << lane) - 1ull;   // bits below this lane

    float aD = 0, aE = 0, aF = 0;
    for (int qi = 0; qi < 8; ++qi) {
        int ql = chunk * 32 + wave * 8 + qi;
        int q = base + ql;
        float2 qp = sh.bq.poss[ql];
        int row = min(max((int)(qp.y * 32.0f), 0), 31);
        int col = min(max((int)(qp.x * 32.0f), 0), 31);
        int pixl = row * 32 + col;
        float2 tp = sh.bq.poss[pixl];
        int cnt = 0;
        __builtin_amdgcn_wave_barrier();
#pragma unroll
        for (int k = 0; k < 16; ++k) {
            float dx = pr[k].x - qp.x, dy = pr[k].y - qp.y;
            float d2 = __fadd_rn(__fmul_rn(dx, dx), __fmul_rn(dy, dy)); // no FMA contraction
            bool pred = (d2 <= 0.01f);
            unsigned long long mask = __ballot(pred);
            if (pred) {
                int slot = cnt + (int)__popcll(mask & lb);
                if (slot < 256)
                    sh.bq.cand[wave][slot] = ((unsigned long long)__float_as_uint(d2) << 32)
                                             | (unsigned int)(k * 64 + lane);
            }
            cnt += (int)__popcll(mask);
        }
        cnt = min(cnt, 256);
        __builtin_amdgcn_wave_barrier();
        int osel = 0;
        for (int cb = 0; cb < cnt; cb += 64) {
            int i = cb + lane;
            bool sel = false;
            int j = 0;
            if (i < cnt) {
                unsigned long long key = sh.bq.cand[wave][i];
                j = (int)(key & 0xffffffffu);
                if (cnt <= KNB) {
                    sel = (j != pixl);                 // all in-radius are top-K
                } else {
                    int rank = 0;
                    for (int t = 0; t < cnt; ++t) rank += (sh.bq.cand[wave][t] < key) ? 1 : 0;
                    sel = (rank < KNB) && (j != pixl); // top-K, then remove_self_loops
                }
            }
            unsigned long long mask = __ballot(sel);
            if (sel) {
                int slot = osel + (int)__popcll(mask & lb);
                nbrs[q * KNB + slot] = base + j;
                float rx = sh.bq.poss[j].x - tp.x, ry = sh.bq.poss[j].y - tp.y;
                aD += rx * rx; aE += rx * ry; aF += ry * ry;
                atomicAdd(&sh.bq.accd[j], 1.0f);
                atomicAdd(&sh.bq.accx[j], tp.x);
                atomicAdd(&sh.bq.accy[j], tp.y);
            }
            osel += (int)__popcll(mask);
        }
        if (lane == 0) nbr_cnt[q] = osel;
    }
#pragma unroll
    for (int o = 1; o < 64; o <<= 1) {
        aD += __shfl_xor(aD, o); aE += __shfl_xor(aE, o); aF += __shfl_xor(aF, o);
    }
    __syncthreads();
    float* pb = &bqpart[bqid * 3076];
    for (int i = tid; i < 1024; i += 256) {
        pb[i] = sh.bq.accd[i]; pb[1024 + i] = sh.bq.accx[i]; pb[2048 + i] = sh.bq.accy[i];
    }
    if (tid == 0) { pb[3072] = aD; pb[3073] = aE; pb[3074] = aF; }   // DEF tails, plain store
}

// ---------------- node GEMM1 + fused nodeagg + BN stats + finalize ----------
__launch_bounds__(512)
__global__ void k_y(const float* __restrict__ x, const float* __restrict__ W1,
                    const float* __restrict__ b1, const float* __restrict__ pos,
                    const float* __restrict__ bqpart,
                    unsigned int* __restrict__ yb, float* __restrict__ partials,
                    const float* __restrict__ gamma, const float* __restrict__ beta,
                    float* __restrict__ scsh, int* __restrict__ kycnt) {
    __shared__ float w1s[64 * 128];
    __shared__ float stage[8][512];
    __shared__ float lsum[515];
    __shared__ float degS[128], stxS[128], styS[128];
    __shared__ float sDEF[3];
    __shared__ int amLast;
    int tid = threadIdx.x;
    int nblock = blockIdx.x * 128;
    for (int i = tid; i < 64 * 128; i += 512) w1s[i] = W1[i];
    for (int i = tid; i < 515; i += 512) lsum[i] = 0.0f;
    if (tid < 128) {                       // fused nodeagg: 32 chunk partials
        int n = nblock + tid;
        int s = n >> 10, off = n & 1023;
        const float* pb = &bqpart[(s * 32) * 3076];
        float d = 0, xx = 0, yy = 0;
        for (int j = 0; j < 32; ++j) {
            d  += pb[j * 3076 + off];
            xx += pb[j * 3076 + 1024 + off];
            yy += pb[j * 3076 + 2048 + off];
        }
        degS[tid] = d; stxS[tid] = xx; styS[tid] = yy;
    }
    __syncthreads();
    int wave = tid >> 6, lane = tid & 63;
    int f0 = 2 * lane, f1 = 2 * lane + 1;
    float b10 = b1[f0], b11 = b1[f1];
    float* st = &stage[wave][0];
    float P0 = 0, Q0 = 0, R0 = 0, S0 = 0, P1 = 0, Q1 = 0, R1 = 0, S1 = 0;
    float sB = 0, sC = 0, sDeg = 0;

    for (int it = 0; it < 2; ++it) {
        int nbase = nblock + (wave * 2 + it) * 8;
        __builtin_amdgcn_wave_barrier();
#pragma unroll
        for (int mm = 0; mm < 8; ++mm)
            st[mm * 64 + lane] = x[(nbase + mm) * 64 + lane];
        __builtin_amdgcn_wave_barrier();
        float z0[8], z1[8];
#pragma unroll
        for (int mm = 0; mm < 8; ++mm) { z0[mm] = b10; z1[mm] = b11; }
        for (int k4 = 0; k4 < 16; ++k4) {
            float2 wv0 = *(const float2*)&w1s[(k4 * 4 + 0) * 128 + f0];
            float2 wv1 = *(const float2*)&w1s[(k4 * 4 + 1) * 128 + f0];
            float2 wv2 = *(const float2*)&w1s[(k4 * 4 + 2) * 128 + f0];
            float2 wv3 = *(const float2*)&w1s[(k4 * 4 + 3) * 128 + f0];
#pragma unroll
            for (int mm = 0; mm < 8; ++mm) {
                float4 mk = *(const float4*)&st[mm * 64 + k4 * 4];
                z0[mm] += mk.x * wv0.x + mk.y * wv1.x + mk.z * wv2.x + mk.w * wv3.x;
                z1[mm] += mk.x * wv0.y + mk.y * wv1.y + mk.z * wv2.y + mk.w * wv3.y;
            }
        }
#pragma unroll
        for (int mm = 0; mm < 8; ++mm) {
            int n = nbase + mm;
            int li = n - nblock;
            float dg = degS[li];
            float wgt = 1.0f + dg;
            float Bn = dg * pos[2 * n]     - stxS[li];
            float Cn = dg * pos[2 * n + 1] - styS[li];
            float a = z0[mm], bq = z1[mm];
            P0 += wgt * a;  Q0 += wgt * a * a;  R0 += a * Bn;  S0 += a * Cn;
            P1 += wgt * bq; Q1 += wgt * bq * bq; R1 += bq * Bn; S1 += bq * Cn;
            sB += Bn; sC += Cn; sDeg += dg;
            yb[n * 64 + lane] = pack_bf2(a, bq);
        }
        __builtin_amdgcn_wave_barrier();
    }
    atomicAdd(&lsum[f0], P0);        atomicAdd(&lsum[f1], P1);
    atomicAdd(&lsum[128 + f0], Q0);  atomicAdd(&lsum[128 + f1], Q1);
    atomicAdd(&lsum[256 + f0], R0);  atomicAdd(&lsum[256 + f1], R1);
    atomicAdd(&lsum[384 + f0], S0);  atomicAdd(&lsum[384 + f1], S1);
    if (lane == 0) {
        atomicAdd(&lsum[512], sB);
        atomicAdd(&lsum[513], sC);
        atomicAdd(&lsum[514], sDeg);
    }
    __syncthreads();
    for (int i = tid; i < 515; i += 512) partials[blockIdx.x * 516 + i] = lsum[i];
    // ---- last-block finalize (fence once per block; no hot-loop fences) ----
    __threadfence();
    if (tid == 0) amLast = (atomicAdd(kycnt, 1) == 255) ? 1 : 0;
    __syncthreads();
    if (!amLast) return;
    __threadfence();
    if (tid < 3) sDEF[tid] = 0.0f;
    __syncthreads();
    for (int i = tid; i < 515; i += 512) {
        float s = 0;
        for (int b = 0; b < 256; ++b) s += partials[b * 516 + i];
        lsum[i] = s;
    }
    {   // sum the 1024 per-block DEF tails
        float td = 0, te = 0, tf = 0;
        for (int b = tid; b < 1024; b += 512) {
            const float* pb = &bqpart[b * 3076 + 3072];
            td += pb[0]; te += pb[1]; tf += pb[2];
        }
        atomicAdd(&sDEF[0], td); atomicAdd(&sDEF[1], te); atomicAdd(&sDEF[2], tf);
    }
    __syncthreads();
    if (tid < 128) {
        int f = tid;
        float P = lsum[f], Q = lsum[128 + f], R = lsum[256 + f], S = lsum[384 + f];
        float SB = lsum[512], SC = lsum[513], SDeg = lsum[514];
        float u = W1[8192 + f], v = W1[8320 + f];
        float cntv = 32768.0f + SDeg;
        float mean = (P + u * SB + v * SC) / cntv;
        float E2 = (Q + 2.0f * u * R + 2.0f * v * S
                    + u * u * sDEF[0] + 2.0f * u * v * sDEF[1] + v * v * sDEF[2]) / cntv;
        float var = E2 - mean * mean;
        float sc = gamma[f] / sqrtf(var + BN_EPS);
        scsh[f] = sc;
        scsh[128 + f] = beta[f] - mean * sc;
    }
}

// ---------- self pass (MFMA f16) + w/shp precompute (fp16) ------------------
__launch_bounds__(256)
__global__ void k_self(const unsigned int* __restrict__ yb, const float* __restrict__ pos,
                       const float* __restrict__ W1, const float* __restrict__ scsh,
                       const unsigned short* __restrict__ w2b, const float* __restrict__ b2,
                       const int* __restrict__ qcnt,
                       unsigned int* __restrict__ wbuf, unsigned int* __restrict__ shpbuf,
                       float* __restrict__ selfbuf, float* __restrict__ out) {
    __shared__ unsigned short hbuf[4][16 * 136];   // 272 B row stride
    int tid = threadIdx.x, wave = tid >> 6, lane = tid & 63;
    unsigned short* hb = hbuf[wave];
    half8 bfrag[4][4];
#pragma unroll
    for (int t = 0; t < 4; ++t)
#pragma unroll
        for (int ks = 0; ks < 4; ++ks)
            bfrag[t][ks] = *(const half8*)&w2b[((t * 4 + ks) * 64 + lane) * 8];
    int f0 = 2 * lane;
    float sc0 = scsh[f0],     sh0 = scsh[128 + f0];
    float sc1 = scsh[f0 + 1], sh1 = scsh[129 + f0];
    float u0 = W1[8192 + f0], v0 = W1[8320 + f0];
    float u1 = W1[8193 + f0], v1 = W1[8321 + f0];
    float b2v0 = b2[(lane & 15)],      b2v1 = b2[16 + (lane & 15)];
    float b2v2 = b2[32 + (lane & 15)], b2v3 = b2[48 + (lane & 15)];

    int nbase = (blockIdx.x * 4 + wave) * 16;
#pragma unroll
    for (int c = 0; c < 2; ++c) {
        unsigned int yw[8];
#pragma unroll
        for (int j = 0; j < 8; ++j)
            yw[j] = yb[(nbase + c * 8 + j) * 64 + lane];
#pragma unroll
        for (int j = 0; j < 8; ++j) {
            int e = c * 8 + j;
            int nn = nbase + e;
            float y0 = bf_lo(yw[j]), y1 = bf_hi(yw[j]);
            float h0 = fmaxf(y0 * sc0 + sh0, 0.0f);
            float h1 = fmaxf(y1 * sc1 + sh1, 0.0f);
            *(unsigned int*)&hb[e * 136 + f0] = pack_h2(h0, h1);
            float px = pos[2 * nn], py = pos[2 * nn + 1];
            float ts0 = (px * u0 + py * v0) * sc0;
            float ts1 = (px * u1 + py * v1) * sc1;
            wbuf[nn * 64 + lane]   = pack_h2(y0 * sc0 + ts0, y1 * sc1 + ts1);
            shpbuf[nn * 64 + lane] = pack_h2(sh0 - ts0, sh1 - ts1);
        }
    }
    __builtin_amdgcn_wave_barrier();
    floatx4 acc0 = {0,0,0,0}, acc1 = {0,0,0,0}, acc2 = {0,0,0,0}, acc3 = {0,0,0,0};
#pragma unroll
    for (int ks = 0; ks < 4; ++ks) {
        half8 a = *(const half8*)&hb[(lane & 15) * 136 + ks * 32 + (lane >> 4) * 8];
        acc0 = __builtin_amdgcn_mfma_f32_16x16x32_f16(a, bfrag[0][ks], acc0, 0, 0, 0);
        acc1 = __builtin_amdgcn_mfma_f32_16x16x32_f16(a, bfrag[1][ks], acc1, 0, 0, 0);
        acc2 = __builtin_amdgcn_mfma_f32_16x16x32_f16(a, bfrag[2][ks], acc2, 0, 0, 0);
        acc3 = __builtin_amdgcn_mfma_f32_16x16x32_f16(a, bfrag[3][ks], acc3, 0, 0, 0);
    }
    int nrow = nbase + (lane >> 4) * 4;
#pragma unroll
    for (int r = 0; r < 4; ++r) {
        int n = nrow + r;
        float o0 = acc0[r] + b2v0, o1 = acc1[r] + b2v1;
        float o2 = acc2[r] + b2v2, o3 = acc3[r] + b2v3;
        selfbuf[n * 64 + (lane & 15)]      = o0;   // contiguous copy for k_gather
        selfbuf[n * 64 + 16 + (lane & 15)] = o1;
        selfbuf[n * 64 + 32 + (lane & 15)] = o2;
        selfbuf[n * 64 + 48 + (lane & 15)] = o3;
        if (qcnt[n] == 0) {                 // k_gather overwrites qcnt>0 nodes
            int obase = (n >> 10) * 65536 + (n & 1023);
            out[obase + ((lane & 15)) * 1024]      = o0;
            out[obase + (16 + (lane & 15)) * 1024] = o1;
            out[obase + (32 + (lane & 15)) * 1024] = o2;
            out[obase + (48 + (lane & 15)) * 1024] = o3;
        }
    }
}

// ---------- neighbor pass: LDS-free, XCD-swizzled for L2 locality -----------
__launch_bounds__(256)
__global__ void k_out(const unsigned int* __restrict__ wbuf,
                      const unsigned int* __restrict__ shpbuf,
                      const float* __restrict__ pos,
                      const unsigned short* __restrict__ w2b, const float* __restrict__ b2,
                      const int* __restrict__ nbrs, const int* __restrict__ nbr_cnt,
                      const int* __restrict__ islot, float* __restrict__ scratch) {
    int tid = threadIdx.x, wave = tid >> 6, lane = tid & 63;
    // XCD swizzle: all 128 blocks of a sample share blockIdx%8 (one XCD),
    // so the sample's wbuf/shp/nbrs/scratch slices stay in that XCD's L2.
    int g8 = blockIdx.x & 7;
    int r  = blockIdx.x >> 3;            // 0..511
    int s_idx  = g8 + 8 * (r >> 7);      // sample 0..31
    int within = r & 127;                // block within sample
    int lblock = s_idx * 128 + within;   // logical block 0..4095
    half8 bfrag[4][4];
#pragma unroll
    for (int t = 0; t < 4; ++t)
#pragma unroll
        for (int ks = 0; ks < 4; ++ks)
            bfrag[t][ks] = *(const half8*)&w2b[((t * 4 + ks) * 64 + lane) * 8];
    float b2l = b2[lane];
    int em = lane & 15;                  // edge-in-tile this lane's A-frag covers
    int koff = (lane >> 4) * 4;          // dword offset of this lane's 8 features
    int wid = lblock * 4 + wave;         // 16384 waves, 2 queries each

    for (int qi = 0; qi < 2; ++qi) {
        int q = wid * 2 + qi;
        int m = nbr_cnt[q];              // m <= 32
        int b = q >> 10;
        float om0[4], om1[4], om2[4], om3[4];
#pragma unroll
        for (int r4 = 0; r4 < 4; ++r4) { om0[r4] = -INFINITY; om1[r4] = -INFINITY; om2[r4] = -INFINITY; om3[r4] = -INFINITY; }
        float qx = pos[2 * q], qy = pos[2 * q + 1];
        int row = min(max((int)(qy * 32.0f), 0), 31);
        int col = min(max((int)(qx * 32.0f), 0), 31);
        int pixq = (b << 10) + row * 32 + col;

        if (m > 0) {
            uint4 sv[4];
#pragma unroll
            for (int ks = 0; ks < 4; ++ks)
                sv[ks] = *(const uint4*)&shpbuf[pixq * 64 + ks * 16 + koff];
            int nv = (lane < m) ? nbrs[q * KNB + lane] : 0;
            int src0 = __shfl(nv, em);
            int src1 = __shfl(nv, 16 + em);
            bool two = (m > 16);
            uint4 g0[4], g1[4];
            const unsigned int* wp0 = &wbuf[src0 * 64 + koff];
#pragma unroll
            for (int ks = 0; ks < 4; ++ks) g0[ks] = *(const uint4*)&wp0[ks * 16];
            if (two) {
                const unsigned int* wp1 = &wbuf[src1 * 64 + koff];
#pragma unroll
                for (int ks = 0; ks < 4; ++ks) g1[ks] = *(const uint4*)&wp1[ks * 16];
            }
            int rowb = (lane >> 4) * 4;
            // ---- tile 0 ----
            {
                floatx4 a0 = {0,0,0,0}, a1 = {0,0,0,0}, a2 = {0,0,0,0}, a3 = {0,0,0,0};
#pragma unroll
                for (int ks = 0; ks < 4; ++ks) {
                    union { unsigned int u[4]; half8 h8; } af;
#pragma unroll
                    for (int qd = 0; qd < 4; ++qd) {
                        unsigned int wd = (qd == 0) ? g0[ks].x : (qd == 1) ? g0[ks].y : (qd == 2) ? g0[ks].z : g0[ks].w;
                        unsigned int sd = (qd == 0) ? sv[ks].x : (qd == 1) ? sv[ks].y : (qd == 2) ? sv[ks].z : sv[ks].w;
                        half2v wh = *reinterpret_cast<half2v*>(&wd);
                        half2v shh = *reinterpret_cast<half2v*>(&sd);
                        half2v zz = { (_Float16)0.0f, (_Float16)0.0f };
                        half2v hh = __builtin_elementwise_max(wh + shh, zz);
                        af.u[qd] = *reinterpret_cast<unsigned int*>(&hh);
                    }
                    a0 = __builtin_amdgcn_mfma_f32_16x16x32_f16(af.h8, bfrag[0][ks], a0, 0, 0, 0);
                    a1 = __builtin_amdgcn_mfma_f32_16x16x32_f16(af.h8, bfrag[1][ks], a1, 0, 0, 0);
                    a2 = __builtin_amdgcn_mfma_f32_16x16x32_f16(af.h8, bfrag[2][ks], a2, 0, 0, 0);
                    a3 = __builtin_amdgcn_mfma_f32_16x16x32_f16(af.h8, bfrag[3][ks], a3, 0, 0, 0);
                }
#pragma unroll
                for (int r4 = 0; r4 < 4; ++r4) {
                    if (rowb + r4 < m) {
                        om0[r4] = fmaxf(om0[r4], a0[r4]);
                        om1[r4] = fmaxf(om1[r4], a1[r4]);
                        om2[r4] = fmaxf(om2[r4], a2[r4]);
                        om3[r4] = fmaxf(om3[r4], a3[r4]);
                    }
                }
            }
            // ---- tile 1 ----
            if (two) {
                floatx4 a0 = {0,0,0,0}, a1 = {0,0,0,0}, a2 = {0,0,0,0}, a3 = {0,0,0,0};
#pragma unroll
                for (int ks = 0; ks < 4; ++ks) {
                    union { unsigned int u[4]; half8 h8; } af;
#pragma unroll
                    for (int qd = 0; qd < 4; ++qd) {
                        unsigned int wd = (qd == 0) ? g1[ks].x : (qd == 1) ? g1[ks].y : (qd == 2) ? g1[ks].z : g1[ks].w;
                        unsigned int sd = (qd == 0) ? sv[ks].x : (qd == 1) ? sv[ks].y : (qd == 2) ? sv[ks].z : sv[ks].w;
                        half2v wh = *reinterpret_cast<half2v*>(&wd);
                        half2v shh = *reinterpret_cast<half2v*>(&sd);
                        half2v zz = { (_Float16)0.0f, (_Float16)0.0f };
                        half2v hh = __builtin_elementwise_max(wh + shh, zz);
                        af.u[qd] = *reinterpret_cast<unsigned int*>(&hh);
                    }
                    a0 = __builtin_amdgcn_mfma_f32_16x16x32_f16(af.h8, bfrag[0][ks], a0, 0, 0, 0);
                    a1 = __builtin_amdgcn_mfma_f32_16x16x32_f16(af.h8, bfrag[1][ks], a1, 0, 0, 0);
                    a2 = __builtin_amdgcn_mfma_f32_16x16x32_f16(af.h8, bfrag[2][ks], a2, 0, 0, 0);
                    a3 = __builtin_amdgcn_mfma_f32_16x16x32_f16(af.h8, bfrag[3][ks], a3, 0, 0, 0);
                }
#pragma unroll
                for (int r4 = 0; r4 < 4; ++r4) {
                    int e = 16 + rowb + r4;
                    if (e < m) {
                        om0[r4] = fmaxf(om0[r4], a0[r4]);
                        om1[r4] = fmaxf(om1[r4], a1[r4]);
                        om2[r4] = fmaxf(om2[r4], a2[r4]);
                        om3[r4] = fmaxf(om3[r4], a3[r4]);
                    }
                }
            }
        }
        float w0 = fmaxf(fmaxf(om0[0], om0[1]), fmaxf(om0[2], om0[3]));
        float w1 = fmaxf(fmaxf(om1[0], om1[1]), fmaxf(om1[2], om1[3]));
        float w2 = fmaxf(fmaxf(om2[0], om2[1]), fmaxf(om2[2], om2[3]));
        float w3 = fmaxf(fmaxf(om3[0], om3[1]), fmaxf(om3[2], om3[3]));
        w0 = fmaxf(w0, __shfl_xor(w0, 16)); w0 = fmaxf(w0, __shfl_xor(w0, 32));
        w1 = fmaxf(w1, __shfl_xor(w1, 16)); w1 = fmaxf(w1, __shfl_xor(w1, 32));
        w2 = fmaxf(w2, __shfl_xor(w2, 16)); w2 = fmaxf(w2, __shfl_xor(w2, 32));
        w3 = fmaxf(w3, __shfl_xor(w3, 16)); w3 = fmaxf(w3, __shfl_xor(w3, 32));
        int g4 = lane >> 4;   // feature = g4*16 + (lane&15) = lane
        float vf = (g4 == 0) ? w0 : (g4 == 1) ? w1 : (g4 == 2) ? w2 : w3;
        vf += b2l;            // m==0 -> -inf: ignored by k_gather's max
        scratch[islot[q] * 64 + lane] = vf;    // plain coalesced store, no atomics
    }
}

// ---------- gather: per pixel, max(self, contiguous query slots) ------------
__launch_bounds__(256)
__global__ void k_gather(const float* __restrict__ scratch, const float* __restrict__ selfbuf,
                         const int* __restrict__ qcnt, const int* __restrict__ qstart,
                         float* __restrict__ out) {
    int tid = threadIdx.x, wave = tid >> 6, lane = tid & 63;
    int n = blockIdx.x * 4 + wave;
    int c = qcnt[n];
    if (c == 0) return;                  // out written by k_self
    int qs = qstart[n];
    float v = selfbuf[n * 64 + lane];
    for (int i = 0; i < c; ++i)
        v = fmaxf(v, scratch[(qs + i) * 64 + lane]);
    out[(n >> 10) * 65536 + lane * 1024 + (n & 1023)] = v;
}

extern "C" void kernel_launch(void* const* d_in, const int* in_sizes, int n_in,
                              void* d_out, int out_size, void* d_ws, size_t ws_size,
                              hipStream_t stream) {
    const float* x     = (const float*)d_in[0];
    const float* pos   = (const float*)d_in[1];
    // d_in[2] = batch (unused: points are sorted, b = idx >> 10)
    const float* W1    = (const float*)d_in[3];
    const float* b1    = (const float*)d_in[4];
    const float* gamma = (const float*)d_in[5];
    const float* beta  = (const float*)d_in[6];
    const float* W2    = (const float*)d_in[7];
    const float* b2    = (const float*)d_in[8];
    float* out = (float*)d_out;
    char* ws = (char*)d_ws;
    int*   nbrs     = (int*)(ws + WS_NBRS);
    int*   nbr_cnt  = (int*)(ws + WS_NBRCNT);
    int*   kycnt    = (int*)(ws + WS_KYCNT);
    float* scsh     = (float*)(ws + WS_SCSH);
    unsigned short* w2b = (unsigned short*)(ws + WS_W2B);
    float* partials = (float*)(ws + WS_PART);
    unsigned int* yb = (unsigned int*)(ws + WS_Y);
    float* scratch  = (float*)(ws + WS_SCRATCH);        // overlays yb (dead after k_self)
    unsigned int* wbuf = (unsigned int*)(ws + WS_WB);
    int* qcnt   = (int*)(ws + WS_QCNT);
    int* qstart = (int*)(ws + WS_QSTART);
    int* qlist  = (int*)(ws + WS_QLIST);
    int* islot  = (int*)(ws + WS_ISLOT);
    float* selfbuf = (float*)(ws + WS_SELF);
    unsigned int* shpbuf = (unsigned int*)(ws + WS_SHP);
    float* bqpart   = (float*)(ws + WS_BQPART);         // overlays self+shp (dead before k_self)

    k_bq<<<1056, 256, 0, stream>>>(pos, nbrs, nbr_cnt, bqpart, W2, w2b,
                                   qcnt, qstart, qlist, islot, kycnt);
    k_y<<<256, 512, 0, stream>>>(x, W1, b1, pos, bqpart, yb, partials,
                                 gamma, beta, scsh, kycnt);
    k_self<<<NPTS / 64, 256, 0, stream>>>(yb, pos, W1, scsh, w2b, b2, qcnt,
                                          wbuf, shpbuf, selfbuf, out);
    k_out<<<NPTS / 8, 256, 0, stream>>>(wbuf, shpbuf, pos, w2b, b2,
                                        nbrs, nbr_cnt, islot, scratch);
    k_gather<<<NPTS / 4, 256, 0, stream>>>(scratch, selfbuf, qcnt, qstart, out);
}

// Round 15
// 252.463 us; speedup vs baseline: 6.8549x; 1.1003x over previous
//
#include <hip/hip_runtime.h>
#include <hip/hip_bf16.h>
#include <hip/hip_fp16.h>
#include <math.h>

// ---------------------------------------------------------------------------
// PointsToImage: ball-query (K=32, R=0.1) -> PointNetConv msg=[x_j, pos_j-pos_dst]
// -> Linear(66,128) -> masked-BatchNorm -> ReLU -> Linear(128,64) -> scatter-max
// into pixel nodes, output [B=32, F=64, 32, 32] fp32.
//
// R15: R14's per-block __threadfence in k_y flushed L2 256x (k_y 92 us,
// VALUBusy 11%). Finalize de-fused back to a 1-block kernel; k_y fence-free
// (R12 form). KEPT: prep fused in k_bq, XCD-aware swizzle in k_out (sample's
// wbuf/shp/nbrs/scratch slices pinned to one XCD's L2).
// Pipeline (6 launches): k_bq -> k_y -> k_finalize -> k_self -> k_out -> k_gather
// ---------------------------------------------------------------------------

#define NPTS   32768
#define KNB    32
#define BN_EPS 1e-5f

// workspace layout (bytes)
#define WS_NBRS     0u           // int[NPTS*KNB]      = 4194304
#define WS_NBRCNT   4194304u     // int[NPTS]          = 131072
#define WS_SCSH     4719616u     // float[256]
#define WS_W2B      4720640u     // ushort[8192]       (W2 B-frag, fp16)
#define WS_PART     4737024u     // float[256*516]     = 528384
#define WS_Y        5265408u     // uint[NPTS*64]      = 8388608 (yb; dead after k_self)
#define WS_SCRATCH  5265408u     // float[NPTS*64]     (OVERLAYS yb)
#define WS_WB       13654016u    // uint[NPTS*64]      = 8388608 (w, fp16 pairs)
#define WS_QCNT     22042624u    // int[NPTS]
#define WS_QSTART   22173696u    // int[NPTS]
#define WS_QLIST    22304768u    // int[NPTS]
#define WS_ISLOT    22435840u    // int[NPTS]
#define WS_SELF     22566912u    // float[NPTS*64]     = 8388608
#define WS_SHP      30955520u    // uint[NPTS*64]      = 8388608 (shp, fp16 pairs)
#define WS_BQPART   22566912u    // float[1024*3076]   = 12599296 (OVERLAYS self+shp;
                                 //   dead after k_finalize, before k_self writes)

typedef __attribute__((ext_vector_type(8))) _Float16 half8;
typedef __attribute__((ext_vector_type(2))) _Float16 half2v;
typedef __attribute__((ext_vector_type(4))) float floatx4;

__device__ __forceinline__ unsigned short f2h_bits(float f) {
    _Float16 h = (_Float16)f;
    return *reinterpret_cast<unsigned short*>(&h);
}
__device__ __forceinline__ float bf_lo(unsigned int w) { return __uint_as_float(w << 16); }
__device__ __forceinline__ float bf_hi(unsigned int w) { return __uint_as_float(w & 0xffff0000u); }
__device__ __forceinline__ unsigned int pack_bf2(float lo, float hi) {
    __hip_bfloat162 hh = __float22bfloat162_rn(make_float2(lo, hi));
    return *reinterpret_cast<unsigned int*>(&hh);
}
__device__ __forceinline__ unsigned int pack_h2(float lo, float hi) {
    half2v hh = { (_Float16)lo, (_Float16)hi };
    return *reinterpret_cast<unsigned int*>(&hh);
}

// ------------- fused prep + ball query (1056 blocks) ------------------------
union ShBQ {
    struct {
        float2 poss[1024];
        float accd[1024], accx[1024], accy[1024];
        unsigned long long cand[4][256];
    } bq;                                             // 28672 B
    struct {
        int cntS[1024], preS[1024], offS[1024], pixOf[1024];
        int wtot[4];
    } pm;                                             // 16400 B
};

__launch_bounds__(256)
__global__ void k_bq(const float* __restrict__ pos,
                     int* __restrict__ nbrs, int* __restrict__ nbr_cnt,
                     float* __restrict__ bqpart,
                     const float* __restrict__ W2, unsigned short* __restrict__ w2b,
                     int* __restrict__ qcnt, int* __restrict__ qstart,
                     int* __restrict__ qlist, int* __restrict__ islot) {
    __shared__ ShBQ sh;
    int tid = threadIdx.x;

    if (blockIdx.x < 32) {
        // ---------------- prep path ----------------
        int s = blockIdx.x;
        int gt = s * 256 + tid;            // 8192 total
        {   // W2 pack: B-frag lane L holds B[k=(L>>4)*8+j][n=L&15]
            int j  = gt & 7;
            int L  = (gt >> 3) & 63;
            int ks = (gt >> 9) & 3;
            int t4 = gt >> 11;
            int k = ks * 32 + (L >> 4) * 8 + j;
            int n = t4 * 16 + (L & 15);
            w2b[gt] = f2h_bits(W2[k * 64 + n]);
        }
        int base = s << 10;
        for (int i = tid; i < 1024; i += 256) sh.pm.cntS[i] = 0;
        __syncthreads();
        for (int ql = tid; ql < 1024; ql += 256) {
            float2 p = *(const float2*)&pos[2 * (base + ql)];
            int row = min(max((int)(p.y * 32.0f), 0), 31);
            int col = min(max((int)(p.x * 32.0f), 0), 31);
            int pixl = row * 32 + col;
            sh.pm.pixOf[ql] = pixl;
            atomicAdd(&sh.pm.cntS[pixl], 1);
        }
        __syncthreads();
        int a0 = sh.pm.cntS[4 * tid], a1 = sh.pm.cntS[4 * tid + 1];
        int a2 = sh.pm.cntS[4 * tid + 2], a3 = sh.pm.cntS[4 * tid + 3];
        int tsum = a0 + a1 + a2 + a3;
        int lane = tid & 63, wv = tid >> 6;
        int v = tsum;
        for (int o = 1; o < 64; o <<= 1) { int u = __shfl_up(v, o); if (lane >= o) v += u; }
        if (lane == 63) sh.pm.wtot[wv] = v;
        __syncthreads();
        int wbase = 0;
        for (int w = 0; w < wv; ++w) wbase += sh.pm.wtot[w];
        int excl = wbase + v - tsum;
        sh.pm.preS[4 * tid] = excl;
        sh.pm.preS[4 * tid + 1] = excl + a0;
        sh.pm.preS[4 * tid + 2] = excl + a0 + a1;
        sh.pm.preS[4 * tid + 3] = excl + a0 + a1 + a2;
        __syncthreads();
        for (int i = tid; i < 1024; i += 256) sh.pm.offS[i] = sh.pm.preS[i];
        __syncthreads();
        for (int ql = tid; ql < 1024; ql += 256) {
            int p = sh.pm.pixOf[ql];
            int slot = atomicAdd(&sh.pm.offS[p], 1);
            qlist[base + slot] = base + ql;
            islot[base + ql] = base + slot;
        }
        for (int i = tid; i < 1024; i += 256) {
            qcnt[base + i] = sh.pm.cntS[i];
            qstart[base + i] = base + sh.pm.preS[i];
        }
        return;
    }

    // ---------------- ball query path ----------------
    int bqid = blockIdx.x - 32;        // 0..1023
    int wave = tid >> 6, lane = tid & 63;
    int s = bqid >> 5;                 // sample
    int chunk = bqid & 31;             // 32 chunks of 32 queries
    int base = s << 10;
    for (int i = tid; i < 1024; i += 256) sh.bq.poss[i] = *(const float2*)&pos[2 * (base + i)];
    for (int i = tid; i < 1024; i += 256) { sh.bq.accd[i] = 0.0f; sh.bq.accx[i] = 0.0f; sh.bq.accy[i] = 0.0f; }
    __syncthreads();
    float2 pr[16];
#pragma unroll
    for (int k = 0; k < 16; ++k) pr[k] = sh.bq.poss[k * 64 + lane];
    unsigned long long lb = (1ull << lane) - 1ull;   // bits below this lane

    float aD = 0, aE = 0, aF = 0;
    for (int qi = 0; qi < 8; ++qi) {
        int ql = chunk * 32 + wave * 8 + qi;
        int q = base + ql;
        float2 qp = sh.bq.poss[ql];
        int row = min(max((int)(qp.y * 32.0f), 0), 31);
        int col = min(max((int)(qp.x * 32.0f), 0), 31);
        int pixl = row * 32 + col;
        float2 tp = sh.bq.poss[pixl];
        int cnt = 0;
        __builtin_amdgcn_wave_barrier();
#pragma unroll
        for (int k = 0; k < 16; ++k) {
            float dx = pr[k].x - qp.x, dy = pr[k].y - qp.y;
            float d2 = __fadd_rn(__fmul_rn(dx, dx), __fmul_rn(dy, dy)); // no FMA contraction
            bool pred = (d2 <= 0.01f);
            unsigned long long mask = __ballot(pred);
            if (pred) {
                int slot = cnt + (int)__popcll(mask & lb);
                if (slot < 256)
                    sh.bq.cand[wave][slot] = ((unsigned long long)__float_as_uint(d2) << 32)
                                             | (unsigned int)(k * 64 + lane);
            }
            cnt += (int)__popcll(mask);
        }
        cnt = min(cnt, 256);
        __builtin_amdgcn_wave_barrier();
        int osel = 0;
        for (int cb = 0; cb < cnt; cb += 64) {
            int i = cb + lane;
            bool sel = false;
            int j = 0;
            if (i < cnt) {
                unsigned long long key = sh.bq.cand[wave][i];
                j = (int)(key & 0xffffffffu);
                if (cnt <= KNB) {
                    sel = (j != pixl);                 // all in-radius are top-K
                } else {
                    int rank = 0;
                    for (int t = 0; t < cnt; ++t) rank += (sh.bq.cand[wave][t] < key) ? 1 : 0;
                    sel = (rank < KNB) && (j != pixl); // top-K, then remove_self_loops
                }
            }
            unsigned long long mask = __ballot(sel);
            if (sel) {
                int slot = osel + (int)__popcll(mask & lb);
                nbrs[q * KNB + slot] = base + j;
                float rx = sh.bq.poss[j].x - tp.x, ry = sh.bq.poss[j].y - tp.y;
                aD += rx * rx; aE += rx * ry; aF += ry * ry;
                atomicAdd(&sh.bq.accd[j], 1.0f);
                atomicAdd(&sh.bq.accx[j], tp.x);
                atomicAdd(&sh.bq.accy[j], tp.y);
            }
            osel += (int)__popcll(mask);
        }
        if (lane == 0) nbr_cnt[q] = osel;
    }
#pragma unroll
    for (int o = 1; o < 64; o <<= 1) {
        aD += __shfl_xor(aD, o); aE += __shfl_xor(aE, o); aF += __shfl_xor(aF, o);
    }
    __syncthreads();
    float* pb = &bqpart[bqid * 3076];
    for (int i = tid; i < 1024; i += 256) {
        pb[i] = sh.bq.accd[i]; pb[1024 + i] = sh.bq.accx[i]; pb[2048 + i] = sh.bq.accy[i];
    }
    if (tid == 0) { pb[3072] = aD; pb[3073] = aE; pb[3074] = aF; }   // DEF tails, plain store
}

// ---------------- node GEMM1 + fused nodeagg + BN node-stats ----------------
// 256 blocks x 512 threads; block = 128 nodes; lane owns f0=2l, f1=2l+1.
__launch_bounds__(512)
__global__ void k_y(const float* __restrict__ x, const float* __restrict__ W1,
                    const float* __restrict__ b1, const float* __restrict__ pos,
                    const float* __restrict__ bqpart,
                    unsigned int* __restrict__ yb, float* __restrict__ partials) {
    __shared__ float w1s[64 * 128];
    __shared__ float stage[8][512];
    __shared__ float lsum[515];
    __shared__ float degS[128], stxS[128], styS[128];
    int tid = threadIdx.x;
    int nblock = blockIdx.x * 128;
    for (int i = tid; i < 64 * 128; i += 512) w1s[i] = W1[i];
    for (int i = tid; i < 515; i += 512) lsum[i] = 0.0f;
    if (tid < 128) {                       // fused nodeagg: 32 chunk partials
        int n = nblock + tid;
        int s = n >> 10, off = n & 1023;
        const float* pb = &bqpart[(s * 32) * 3076];
        float d = 0, xx = 0, yy = 0;
        for (int j = 0; j < 32; ++j) {
            d  += pb[j * 3076 + off];
            xx += pb[j * 3076 + 1024 + off];
            yy += pb[j * 3076 + 2048 + off];
        }
        degS[tid] = d; stxS[tid] = xx; styS[tid] = yy;
    }
    __syncthreads();
    int wave = tid >> 6, lane = tid & 63;
    int f0 = 2 * lane, f1 = 2 * lane + 1;
    float b10 = b1[f0], b11 = b1[f1];
    float* st = &stage[wave][0];
    float P0 = 0, Q0 = 0, R0 = 0, S0 = 0, P1 = 0, Q1 = 0, R1 = 0, S1 = 0;
    float sB = 0, sC = 0, sDeg = 0;

    for (int it = 0; it < 2; ++it) {
        int nbase = nblock + (wave * 2 + it) * 8;
        __builtin_amdgcn_wave_barrier();
#pragma unroll
        for (int mm = 0; mm < 8; ++mm)
            st[mm * 64 + lane] = x[(nbase + mm) * 64 + lane];
        __builtin_amdgcn_wave_barrier();
        float z0[8], z1[8];
#pragma unroll
        for (int mm = 0; mm < 8; ++mm) { z0[mm] = b10; z1[mm] = b11; }
        for (int k4 = 0; k4 < 16; ++k4) {
            float2 wv0 = *(const float2*)&w1s[(k4 * 4 + 0) * 128 + f0];
            float2 wv1 = *(const float2*)&w1s[(k4 * 4 + 1) * 128 + f0];
            float2 wv2 = *(const float2*)&w1s[(k4 * 4 + 2) * 128 + f0];
            float2 wv3 = *(const float2*)&w1s[(k4 * 4 + 3) * 128 + f0];
#pragma unroll
            for (int mm = 0; mm < 8; ++mm) {
                float4 mk = *(const float4*)&st[mm * 64 + k4 * 4];
                z0[mm] += mk.x * wv0.x + mk.y * wv1.x + mk.z * wv2.x + mk.w * wv3.x;
                z1[mm] += mk.x * wv0.y + mk.y * wv1.y + mk.z * wv2.y + mk.w * wv3.y;
            }
        }
#pragma unroll
        for (int mm = 0; mm < 8; ++mm) {
            int n = nbase + mm;
            int li = n - nblock;
            float dg = degS[li];
            float wgt = 1.0f + dg;
            float Bn = dg * pos[2 * n]     - stxS[li];
            float Cn = dg * pos[2 * n + 1] - styS[li];
            float a = z0[mm], bq = z1[mm];
            P0 += wgt * a;  Q0 += wgt * a * a;  R0 += a * Bn;  S0 += a * Cn;
            P1 += wgt * bq; Q1 += wgt * bq * bq; R1 += bq * Bn; S1 += bq * Cn;
            sB += Bn; sC += Cn; sDeg += dg;
            yb[n * 64 + lane] = pack_bf2(a, bq);
        }
        __builtin_amdgcn_wave_barrier();
    }
    atomicAdd(&lsum[f0], P0);        atomicAdd(&lsum[f1], P1);
    atomicAdd(&lsum[128 + f0], Q0);  atomicAdd(&lsum[128 + f1], Q1);
    atomicAdd(&lsum[256 + f0], R0);  atomicAdd(&lsum[256 + f1], R1);
    atomicAdd(&lsum[384 + f0], S0);  atomicAdd(&lsum[384 + f1], S1);
    if (lane == 0) {
        atomicAdd(&lsum[512], sB);
        atomicAdd(&lsum[513], sC);
        atomicAdd(&lsum[514], sDeg);
    }
    __syncthreads();
    for (int i = tid; i < 515; i += 512) partials[blockIdx.x * 516 + i] = lsum[i];
}

// --------------------------- finalize BN scale/shift ------------------------
__global__ void k_finalize(const float* __restrict__ gamma, const float* __restrict__ beta,
                           const float* __restrict__ W1, const float* __restrict__ partials,
                           const float* __restrict__ bqpart, float* __restrict__ scsh) {
    __shared__ float red[515];
    __shared__ float sDEF[3];
    int tid = threadIdx.x;    // 256
    if (tid < 3) sDEF[tid] = 0.0f;
    for (int i = tid; i < 515; i += 256) {
        float s = 0;
        for (int b = 0; b < 256; ++b) s += partials[b * 516 + i];
        red[i] = s;
    }
    __syncthreads();
    {   // sum the 1024 per-block DEF tails
        float td = 0, te = 0, tf = 0;
        for (int b = tid; b < 1024; b += 256) {
            const float* pb = &bqpart[b * 3076 + 3072];
            td += pb[0]; te += pb[1]; tf += pb[2];
        }
        atomicAdd(&sDEF[0], td); atomicAdd(&sDEF[1], te); atomicAdd(&sDEF[2], tf);
    }
    __syncthreads();
    if (tid < 128) {
        int f = tid;
        float P = red[f], Q = red[128 + f], R = red[256 + f], S = red[384 + f];
        float SB = red[512], SC = red[513], SDeg = red[514];
        float u = W1[8192 + f], v = W1[8320 + f];
        float cntv = 32768.0f + SDeg;
        float mean = (P + u * SB + v * SC) / cntv;
        float E2 = (Q + 2.0f * u * R + 2.0f * v * S
                    + u * u * sDEF[0] + 2.0f * u * v * sDEF[1] + v * v * sDEF[2]) / cntv;
        float var = E2 - mean * mean;
        float sc = gamma[f] / sqrtf(var + BN_EPS);
        scsh[f] = sc;
        scsh[128 + f] = beta[f] - mean * sc;
    }
}

// ---------- self pass (MFMA f16) + w/shp precompute (fp16) ------------------
__launch_bounds__(256)
__global__ void k_self(const unsigned int* __restrict__ yb, const float* __restrict__ pos,
                       const float* __restrict__ W1, const float* __restrict__ scsh,
                       const unsigned short* __restrict__ w2b, const float* __restrict__ b2,
                       const int* __restrict__ qcnt,
                       unsigned int* __restrict__ wbuf, unsigned int* __restrict__ shpbuf,
                       float* __restrict__ selfbuf, float* __restrict__ out) {
    __shared__ unsigned short hbuf[4][16 * 136];   // 272 B row stride
    int tid = threadIdx.x, wave = tid >> 6, lane = tid & 63;
    unsigned short* hb = hbuf[wave];
    half8 bfrag[4][4];
#pragma unroll
    for (int t = 0; t < 4; ++t)
#pragma unroll
        for (int ks = 0; ks < 4; ++ks)
            bfrag[t][ks] = *(const half8*)&w2b[((t * 4 + ks) * 64 + lane) * 8];
    int f0 = 2 * lane;
    float sc0 = scsh[f0],     sh0 = scsh[128 + f0];
    float sc1 = scsh[f0 + 1], sh1 = scsh[129 + f0];
    float u0 = W1[8192 + f0], v0 = W1[8320 + f0];
    float u1 = W1[8193 + f0], v1 = W1[8321 + f0];
    float b2v0 = b2[(lane & 15)],      b2v1 = b2[16 + (lane & 15)];
    float b2v2 = b2[32 + (lane & 15)], b2v3 = b2[48 + (lane & 15)];

    int nbase = (blockIdx.x * 4 + wave) * 16;
#pragma unroll
    for (int c = 0; c < 2; ++c) {
        unsigned int yw[8];
#pragma unroll
        for (int j = 0; j < 8; ++j)
            yw[j] = yb[(nbase + c * 8 + j) * 64 + lane];
#pragma unroll
        for (int j = 0; j < 8; ++j) {
            int e = c * 8 + j;
            int nn = nbase + e;
            float y0 = bf_lo(yw[j]), y1 = bf_hi(yw[j]);
            float h0 = fmaxf(y0 * sc0 + sh0, 0.0f);
            float h1 = fmaxf(y1 * sc1 + sh1, 0.0f);
            *(unsigned int*)&hb[e * 136 + f0] = pack_h2(h0, h1);
            float px = pos[2 * nn], py = pos[2 * nn + 1];
            float ts0 = (px * u0 + py * v0) * sc0;
            float ts1 = (px * u1 + py * v1) * sc1;
            wbuf[nn * 64 + lane]   = pack_h2(y0 * sc0 + ts0, y1 * sc1 + ts1);
            shpbuf[nn * 64 + lane] = pack_h2(sh0 - ts0, sh1 - ts1);
        }
    }
    __builtin_amdgcn_wave_barrier();
    floatx4 acc0 = {0,0,0,0}, acc1 = {0,0,0,0}, acc2 = {0,0,0,0}, acc3 = {0,0,0,0};
#pragma unroll
    for (int ks = 0; ks < 4; ++ks) {
        half8 a = *(const half8*)&hb[(lane & 15) * 136 + ks * 32 + (lane >> 4) * 8];
        acc0 = __builtin_amdgcn_mfma_f32_16x16x32_f16(a, bfrag[0][ks], acc0, 0, 0, 0);
        acc1 = __builtin_amdgcn_mfma_f32_16x16x32_f16(a, bfrag[1][ks], acc1, 0, 0, 0);
        acc2 = __builtin_amdgcn_mfma_f32_16x16x32_f16(a, bfrag[2][ks], acc2, 0, 0, 0);
        acc3 = __builtin_amdgcn_mfma_f32_16x16x32_f16(a, bfrag[3][ks], acc3, 0, 0, 0);
    }
    int nrow = nbase + (lane >> 4) * 4;
#pragma unroll
    for (int r = 0; r < 4; ++r) {
        int n = nrow + r;
        float o0 = acc0[r] + b2v0, o1 = acc1[r] + b2v1;
        float o2 = acc2[r] + b2v2, o3 = acc3[r] + b2v3;
        selfbuf[n * 64 + (lane & 15)]      = o0;   // contiguous copy for k_gather
        selfbuf[n * 64 + 16 + (lane & 15)] = o1;
        selfbuf[n * 64 + 32 + (lane & 15)] = o2;
        selfbuf[n * 64 + 48 + (lane & 15)] = o3;
        if (qcnt[n] == 0) {                 // k_gather overwrites qcnt>0 nodes
            int obase = (n >> 10) * 65536 + (n & 1023);
            out[obase + ((lane & 15)) * 1024]      = o0;
            out[obase + (16 + (lane & 15)) * 1024] = o1;
            out[obase + (32 + (lane & 15)) * 1024] = o2;
            out[obase + (48 + (lane & 15)) * 1024] = o3;
        }
    }
}

// ---------- neighbor pass: LDS-free, XCD-swizzled for L2 locality -----------
__launch_bounds__(256)
__global__ void k_out(const unsigned int* __restrict__ wbuf,
                      const unsigned int* __restrict__ shpbuf,
                      const float* __restrict__ pos,
                      const unsigned short* __restrict__ w2b, const float* __restrict__ b2,
                      const int* __restrict__ nbrs, const int* __restrict__ nbr_cnt,
                      const int* __restrict__ islot, float* __restrict__ scratch) {
    int tid = threadIdx.x, wave = tid >> 6, lane = tid & 63;
    // XCD swizzle: all 128 blocks of a sample share blockIdx%8 (one XCD),
    // so the sample's wbuf/shp/nbrs/scratch slices stay in that XCD's L2.
    int g8 = blockIdx.x & 7;
    int r  = blockIdx.x >> 3;            // 0..511
    int s_idx  = g8 + 8 * (r >> 7);      // sample 0..31
    int within = r & 127;                // block within sample
    int lblock = s_idx * 128 + within;   // logical block 0..4095
    half8 bfrag[4][4];
#pragma unroll
    for (int t = 0; t < 4; ++t)
#pragma unroll
        for (int ks = 0; ks < 4; ++ks)
            bfrag[t][ks] = *(const half8*)&w2b[((t * 4 + ks) * 64 + lane) * 8];
    float b2l = b2[lane];
    int em = lane & 15;                  // edge-in-tile this lane's A-frag covers
    int koff = (lane >> 4) * 4;          // dword offset of this lane's 8 features
    int wid = lblock * 4 + wave;         // 16384 waves, 2 queries each

    for (int qi = 0; qi < 2; ++qi) {
        int q = wid * 2 + qi;
        int m = nbr_cnt[q];              // m <= 32
        int b = q >> 10;
        float om0[4], om1[4], om2[4], om3[4];
#pragma unroll
        for (int r4 = 0; r4 < 4; ++r4) { om0[r4] = -INFINITY; om1[r4] = -INFINITY; om2[r4] = -INFINITY; om3[r4] = -INFINITY; }
        float qx = pos[2 * q], qy = pos[2 * q + 1];
        int row = min(max((int)(qy * 32.0f), 0), 31);
        int col = min(max((int)(qx * 32.0f), 0), 31);
        int pixq = (b << 10) + row * 32 + col;

        if (m > 0) {
            uint4 sv[4];
#pragma unroll
            for (int ks = 0; ks < 4; ++ks)
                sv[ks] = *(const uint4*)&shpbuf[pixq * 64 + ks * 16 + koff];
            int nv = (lane < m) ? nbrs[q * KNB + lane] : 0;
            int src0 = __shfl(nv, em);
            int src1 = __shfl(nv, 16 + em);
            bool two = (m > 16);
            uint4 g0[4], g1[4];
            const unsigned int* wp0 = &wbuf[src0 * 64 + koff];
#pragma unroll
            for (int ks = 0; ks < 4; ++ks) g0[ks] = *(const uint4*)&wp0[ks * 16];
            if (two) {
                const unsigned int* wp1 = &wbuf[src1 * 64 + koff];
#pragma unroll
                for (int ks = 0; ks < 4; ++ks) g1[ks] = *(const uint4*)&wp1[ks * 16];
            }
            int rowb = (lane >> 4) * 4;
            // ---- tile 0 ----
            {
                floatx4 a0 = {0,0,0,0}, a1 = {0,0,0,0}, a2 = {0,0,0,0}, a3 = {0,0,0,0};
#pragma unroll
                for (int ks = 0; ks < 4; ++ks) {
                    union { unsigned int u[4]; half8 h8; } af;
#pragma unroll
                    for (int qd = 0; qd < 4; ++qd) {
                        unsigned int wd = (qd == 0) ? g0[ks].x : (qd == 1) ? g0[ks].y : (qd == 2) ? g0[ks].z : g0[ks].w;
                        unsigned int sd = (qd == 0) ? sv[ks].x : (qd == 1) ? sv[ks].y : (qd == 2) ? sv[ks].z : sv[ks].w;
                        half2v wh = *reinterpret_cast<half2v*>(&wd);
                        half2v shh = *reinterpret_cast<half2v*>(&sd);
                        half2v zz = { (_Float16)0.0f, (_Float16)0.0f };
                        half2v hh = __builtin_elementwise_max(wh + shh, zz);
                        af.u[qd] = *reinterpret_cast<unsigned int*>(&hh);
                    }
                    a0 = __builtin_amdgcn_mfma_f32_16x16x32_f16(af.h8, bfrag[0][ks], a0, 0, 0, 0);
                    a1 = __builtin_amdgcn_mfma_f32_16x16x32_f16(af.h8, bfrag[1][ks], a1, 0, 0, 0);
                    a2 = __builtin_amdgcn_mfma_f32_16x16x32_f16(af.h8, bfrag[2][ks], a2, 0, 0, 0);
                    a3 = __builtin_amdgcn_mfma_f32_16x16x32_f16(af.h8, bfrag[3][ks], a3, 0, 0, 0);
                }
#pragma unroll
                for (int r4 = 0; r4 < 4; ++r4) {
                    if (rowb + r4 < m) {
                        om0[r4] = fmaxf(om0[r4], a0[r4]);
                        om1[r4] = fmaxf(om1[r4], a1[r4]);
                        om2[r4] = fmaxf(om2[r4], a2[r4]);
                        om3[r4] = fmaxf(om3[r4], a3[r4]);
                    }
                }
            }
            // ---- tile 1 ----
            if (two) {
                floatx4 a0 = {0,0,0,0}, a1 = {0,0,0,0}, a2 = {0,0,0,0}, a3 = {0,0,0,0};
#pragma unroll
                for (int ks = 0; ks < 4; ++ks) {
                    union { unsigned int u[4]; half8 h8; } af;
#pragma unroll
                    for (int qd = 0; qd < 4; ++qd) {
                        unsigned int wd = (qd == 0) ? g1[ks].x : (qd == 1) ? g1[ks].y : (qd == 2) ? g1[ks].z : g1[ks].w;
                        unsigned int sd = (qd == 0) ? sv[ks].x : (qd == 1) ? sv[ks].y : (qd == 2) ? sv[ks].z : sv[ks].w;
                        half2v wh = *reinterpret_cast<half2v*>(&wd);
                        half2v shh = *reinterpret_cast<half2v*>(&sd);
                        half2v zz = { (_Float16)0.0f, (_Float16)0.0f };
                        half2v hh = __builtin_elementwise_max(wh + shh, zz);
                        af.u[qd] = *reinterpret_cast<unsigned int*>(&hh);
                    }
                    a0 = __builtin_amdgcn_mfma_f32_16x16x32_f16(af.h8, bfrag[0][ks], a0, 0, 0, 0);
                    a1 = __builtin_amdgcn_mfma_f32_16x16x32_f16(af.h8, bfrag[1][ks], a1, 0, 0, 0);
                    a2 = __builtin_amdgcn_mfma_f32_16x16x32_f16(af.h8, bfrag[2][ks], a2, 0, 0, 0);
                    a3 = __builtin_amdgcn_mfma_f32_16x16x32_f16(af.h8, bfrag[3][ks], a3, 0, 0, 0);
                }
#pragma unroll
                for (int r4 = 0; r4 < 4; ++r4) {
                    int e = 16 + rowb + r4;
                    if (e < m) {
                        om0[r4] = fmaxf(om0[r4], a0[r4]);
                        om1[r4] = fmaxf(om1[r4], a1[r4]);
                        om2[r4] = fmaxf(om2[r4], a2[r4]);
                        om3[r4] = fmaxf(om3[r4], a3[r4]);
                    }
                }
            }
        }
        float w0 = fmaxf(fmaxf(om0[0], om0[1]), fmaxf(om0[2], om0[3]));
        float w1 = fmaxf(fmaxf(om1[0], om1[1]), fmaxf(om1[2], om1[3]));
        float w2 = fmaxf(fmaxf(om2[0], om2[1]), fmaxf(om2[2], om2[3]));
        float w3 = fmaxf(fmaxf(om3[0], om3[1]), fmaxf(om3[2], om3[3]));
        w0 = fmaxf(w0, __shfl_xor(w0, 16)); w0 = fmaxf(w0, __shfl_xor(w0, 32));
        w1 = fmaxf(w1, __shfl_xor(w1, 16)); w1 = fmaxf(w1, __shfl_xor(w1, 32));
        w2 = fmaxf(w2, __shfl_xor(w2, 16)); w2 = fmaxf(w2, __shfl_xor(w2, 32));
        w3 = fmaxf(w3, __shfl_xor(w3, 16)); w3 = fmaxf(w3, __shfl_xor(w3, 32));
        int g4 = lane >> 4;   // feature = g4*16 + (lane&15) = lane
        float vf = (g4 == 0) ? w0 : (g4 == 1) ? w1 : (g4 == 2) ? w2 : w3;
        vf += b2l;            // m==0 -> -inf: ignored by k_gather's max
        scratch[islot[q] * 64 + lane] = vf;    // plain coalesced store, no atomics
    }
}

// ---------- gather: per pixel, max(self, contiguous query slots) ------------
__launch_bounds__(256)
__global__ void k_gather(const float* __restrict__ scratch, const float* __restrict__ selfbuf,
                         const int* __restrict__ qcnt, const int* __restrict__ qstart,
                         float* __restrict__ out) {
    int tid = threadIdx.x, wave = tid >> 6, lane = tid & 63;
    int n = blockIdx.x * 4 + wave;
    int c = qcnt[n];
    if (c == 0) return;                  // out written by k_self
    int qs = qstart[n];
    float v = selfbuf[n * 64 + lane];
    for (int i = 0; i < c; ++i)
        v = fmaxf(v, scratch[(qs + i) * 64 + lane]);
    out[(n >> 10) * 65536 + lane * 1024 + (n & 1023)] = v;
}

extern "C" void kernel_launch(void* const* d_in, const int* in_sizes, int n_in,
                              void* d_out, int out_size, void* d_ws, size_t ws_size,
                              hipStream_t stream) {
    const float* x     = (const float*)d_in[0];
    const float* pos   = (const float*)d_in[1];
    // d_in[2] = batch (unused: points are sorted, b = idx >> 10)
    const float* W1    = (const float*)d_in[3];
    const float* b1    = (const float*)d_in[4];
    const float* gamma = (const float*)d_in[5];
    const float* beta  = (const float*)d_in[6];
    const float* W2    = (const float*)d_in[7];
    const float* b2    = (const float*)d_in[8];
    float* out = (float*)d_out;
    char* ws = (char*)d_ws;
    int*   nbrs     = (int*)(ws + WS_NBRS);
    int*   nbr_cnt  = (int*)(ws + WS_NBRCNT);
    float* scsh     = (float*)(ws + WS_SCSH);
    unsigned short* w2b = (unsigned short*)(ws + WS_W2B);
    float* partials = (float*)(ws + WS_PART);
    unsigned int* yb = (unsigned int*)(ws + WS_Y);
    float* scratch  = (float*)(ws + WS_SCRATCH);        // overlays yb (dead after k_self)
    unsigned int* wbuf = (unsigned int*)(ws + WS_WB);
    int* qcnt   = (int*)(ws + WS_QCNT);
    int* qstart = (int*)(ws + WS_QSTART);
    int* qlist  = (int*)(ws + WS_QLIST);
    int* islot  = (int*)(ws + WS_ISLOT);
    float* selfbuf = (float*)(ws + WS_SELF);
    unsigned int* shpbuf = (unsigned int*)(ws + WS_SHP);
    float* bqpart   = (float*)(ws + WS_BQPART);         // overlays self+shp (dead before k_self)

    k_bq<<<1056, 256, 0, stream>>>(pos, nbrs, nbr_cnt, bqpart, W2, w2b,
                                   qcnt, qstart, qlist, islot);
    k_y<<<256, 512, 0, stream>>>(x, W1, b1, pos, bqpart, yb, partials);
    k_finalize<<<1, 256, 0, stream>>>(gamma, beta, W1, partials, bqpart, scsh);
    k_self<<<NPTS / 64, 256, 0, stream>>>(yb, pos, W1, scsh, w2b, b2, qcnt,
                                          wbuf, shpbuf, selfbuf, out);
    k_out<<<NPTS / 8, 256, 0, stream>>>(wbuf, shpbuf, pos, w2b, b2,
                                        nbrs, nbr_cnt, islot, scratch);
    k_gather<<<NPTS / 4, 256, 0, stream>>>(scratch, selfbuf, qcnt, qstart, out);
}